// Round 3
// baseline (1433.321 us; speedup 1.0000x reference)
//
#include <hip/hip_runtime.h>
#include <hip/hip_bf16.h>
#include <cstddef>

#define HW 16384
#define CC 128
#define NB 8
#define GB 4   // batches per group

typedef __hip_bfloat16 bf16;

// ---------------- LayerNorm stats (mean / rstd per (b,p)), all 8 batches ----
__global__ __launch_bounds__(256) void k_ln_stats(const float* __restrict__ x,
                                                  float* __restrict__ mean,
                                                  float* __restrict__ rstd) {
  int idx = blockIdx.x * 256 + threadIdx.x;   // 0 .. 131071
  int b = idx >> 14;
  int p = idx & (HW - 1);
  const float* xp = x + ((size_t)b << 21) + p;
  float s = 0.f, ss = 0.f;
  for (int c = 0; c < CC; ++c) {
    float v = xp[(size_t)c << 14];
    s += v;
    ss += v * v;
  }
  float m = s * (1.0f / CC);
  float var = ss * (1.0f / CC) - m * m;
  mean[idx] = m;
  rstd[idx] = rsqrtf(var + 1e-5f);
}

// ---------------- fused LN + 1x1 conv -> fp32 out (group-local batches) -----
// y[bl,o,p] = r*(Wg x)[o,p] - mu*r*sum(Wg)[o] + bias[o],  b = b0+bl global
__global__ __launch_bounds__(256) void k_conv1x1_ln(
    const float* __restrict__ X, const float* __restrict__ W,
    const float* __restrict__ bias, const float* __restrict__ g,
    const float* __restrict__ mean, const float* __restrict__ rstd,
    float* __restrict__ Y, int b0) {
  __shared__ __align__(16) float As[32][128];   // As[k][m] = W[m][k0+k]*g[k0+k]
  __shared__ __align__(16) float Bs[32][128];   // Bs[k][n] = X[b][k0+k][p0+n]
  const int bl = blockIdx.y;
  const int b = b0 + bl;
  const int p0 = blockIdx.x * 128;
  const int t = threadIdx.x;
  const int m0 = (t >> 4) * 8;
  const int n0 = (t & 15) * 8;
  float acc[8][8];
  float sA[8];
#pragma unroll
  for (int i = 0; i < 8; ++i) {
    sA[i] = 0.f;
#pragma unroll
    for (int j = 0; j < 8; ++j) acc[i][j] = 0.f;
  }
  const float* Xb = X + ((size_t)b << 21);
  const int am = t >> 1, ak = (t & 1) * 16;
  const int bk = t >> 3, bn = (t & 7) * 16;
  for (int k0 = 0; k0 < 128; k0 += 32) {
    const float* wp = W + am * 128 + k0 + ak;
    const float* gp = g + k0 + ak;
#pragma unroll
    for (int j = 0; j < 16; ++j) As[ak + j][am] = wp[j] * gp[j];
    const float* xp = Xb + ((size_t)(k0 + bk) << 14) + p0 + bn;
#pragma unroll
    for (int j = 0; j < 16; ++j) Bs[bk][bn + j] = xp[j];
    __syncthreads();
#pragma unroll
    for (int k = 0; k < 32; ++k) {
      const float4* ap = reinterpret_cast<const float4*>(&As[k][m0]);
      const float4* bp = reinterpret_cast<const float4*>(&Bs[k][n0]);
      float4 a0 = ap[0], a1 = ap[1];
      float4 b0v = bp[0], b1v = bp[1];
      float a[8] = {a0.x, a0.y, a0.z, a0.w, a1.x, a1.y, a1.z, a1.w};
      float bb[8] = {b0v.x, b0v.y, b0v.z, b0v.w, b1v.x, b1v.y, b1v.z, b1v.w};
#pragma unroll
      for (int i = 0; i < 8; ++i) {
        sA[i] += a[i];
#pragma unroll
        for (int j = 0; j < 8; ++j) acc[i][j] = fmaf(a[i], bb[j], acc[i][j]);
      }
    }
    __syncthreads();
  }
  const int pb = b * HW + p0 + n0;
  float mu[8], rs[8];
#pragma unroll
  for (int j = 0; j < 8; ++j) { mu[j] = mean[pb + j]; rs[j] = rstd[pb + j]; }
  float* Yb = Y + ((size_t)bl << 21);
#pragma unroll
  for (int i = 0; i < 8; ++i) {
    const int o = m0 + i;
    const float bo = bias[o];
    float* yp = Yb + ((size_t)o << 14) + p0 + n0;
#pragma unroll
    for (int j = 0; j < 8; ++j)
      yp[j] = rs[j] * acc[i][j] - mu[j] * rs[j] * sA[i] + bo;
  }
}

// ---------------- score GEMM with depthwise-3x3 fused into LDS staging -------
// View identity: Q_view[n,c] = dwq(Yq)[bl, cc=n>>7, h=n&127, w=c] + qdb[cc]
// S[c,d] partial over n-chunk (256 rows) -> P[(ch*GB+bl)]
__global__ __launch_bounds__(256) void k_score_dw(
    const float* __restrict__ Yq, const float* __restrict__ Yk,
    const float* __restrict__ qdw, const float* __restrict__ qdb,
    const float* __restrict__ kdw, const float* __restrict__ kdb,
    float* __restrict__ P) {
  __shared__ __align__(16) float As[32][132];
  __shared__ __align__(16) float Bs[32][132];
  const int ch = blockIdx.x;   // 64 chunks of 256 view-rows
  const int bl = blockIdx.y;
  const int t = threadIdx.x;
  const int m0 = (t >> 4) * 8, n0 = (t & 15) * 8;
  const int h_loc = t >> 3;        // 0..31 : view-row within tile
  const int w0 = (t & 7) * 16;     // 0..112: 16 widths per thread
  float acc[8][8];
#pragma unroll
  for (int i = 0; i < 8; ++i)
#pragma unroll
    for (int j = 0; j < 8; ++j) acc[i][j] = 0.f;
  const float* Yqb = Yq + ((size_t)bl << 21);
  const float* Ykb = Yk + ((size_t)bl << 21);

  for (int k0 = 0; k0 < 256; k0 += 32) {
    const int nb = ch * 256 + k0;
    const int cc = nb >> 7;        // channel (wave-uniform)
    const int h0 = nb & 127;
    const int h = h0 + h_loc;
    // ---- stage both sides with fused dw ----
#pragma unroll
    for (int side = 0; side < 2; ++side) {
      const float* Yc = (side ? Ykb : Yqb) + ((size_t)cc << 14);
      const float* wt = (side ? kdw : qdw) + cc * 9;
      const float bias = (side ? kdb : qdb)[cc];
      float a[16];
#pragma unroll
      for (int j = 0; j < 16; ++j) a[j] = bias;
#pragma unroll
      for (int dy = 0; dy < 3; ++dy) {
        const int hh = h + dy - 1;
        if (hh < 0 || hh > 127) continue;
        const float* rp = Yc + (hh << 7) + w0;
        float4 f0 = *reinterpret_cast<const float4*>(rp);
        float4 f1 = *reinterpret_cast<const float4*>(rp + 4);
        float4 f2 = *reinterpret_cast<const float4*>(rp + 8);
        float4 f3 = *reinterpret_cast<const float4*>(rp + 12);
        float s[18];
        s[1] = f0.x;  s[2] = f0.y;  s[3] = f0.z;  s[4] = f0.w;
        s[5] = f1.x;  s[6] = f1.y;  s[7] = f1.z;  s[8] = f1.w;
        s[9] = f2.x;  s[10] = f2.y; s[11] = f2.z; s[12] = f2.w;
        s[13] = f3.x; s[14] = f3.y; s[15] = f3.z; s[16] = f3.w;
        s[0] = (w0 > 0) ? rp[-1] : 0.f;
        s[17] = (w0 < 112) ? rp[16] : 0.f;
        const float wa = wt[dy * 3 + 0], wb = wt[dy * 3 + 1], wc = wt[dy * 3 + 2];
#pragma unroll
        for (int j = 0; j < 16; ++j)
          a[j] = fmaf(s[j], wa, fmaf(s[j + 1], wb, fmaf(s[j + 2], wc, a[j])));
      }
      float* dst = side ? &Bs[h_loc][w0] : &As[h_loc][w0];
#pragma unroll
      for (int j = 0; j < 16; ++j) dst[j] = a[j];
    }
    __syncthreads();
    // ---- 128x128x32 GEMM step ----
#pragma unroll
    for (int k = 0; k < 32; ++k) {
      const float4* ap = reinterpret_cast<const float4*>(&As[k][m0]);
      const float4* bp = reinterpret_cast<const float4*>(&Bs[k][n0]);
      float4 a0 = ap[0], a1 = ap[1];
      float4 b0v = bp[0], b1v = bp[1];
      float a[8] = {a0.x, a0.y, a0.z, a0.w, a1.x, a1.y, a1.z, a1.w};
      float bb[8] = {b0v.x, b0v.y, b0v.z, b0v.w, b1v.x, b1v.y, b1v.z, b1v.w};
#pragma unroll
      for (int i = 0; i < 8; ++i)
#pragma unroll
        for (int j = 0; j < 8; ++j) acc[i][j] = fmaf(a[i], bb[j], acc[i][j]);
    }
    __syncthreads();
  }
  float* Pp = P + ((size_t)(ch * GB + bl) << 14);
#pragma unroll
  for (int i = 0; i < 8; ++i)
#pragma unroll
    for (int j = 0; j < 8; ++j) Pp[(m0 + i) * 128 + n0 + j] = acc[i][j];
}

// ---------------- reduce split-K partials -> S (GB batches) ----------------
__global__ __launch_bounds__(256) void k_score_reduce(const float* __restrict__ P,
                                                      float* __restrict__ S) {
  int idx = blockIdx.x * 256 + threadIdx.x;   // 0 .. GB*16384-1
  int bl = idx >> 14;
  int rem = idx & 16383;
  float s = 0.f;
  for (int c = 0; c < 64; ++c) s += P[((size_t)(c * GB + bl) << 14) + rem];
  S[idx] = s;
}

// ---------------- softmax over rows of 128 ----------------
__global__ __launch_bounds__(128) void k_softmax(float* __restrict__ S) {
  __shared__ float red[128];
  const int row = blockIdx.x;
  const int t = threadIdx.x;
  float v = S[row * 128 + t];
  red[t] = v;
  __syncthreads();
  for (int s = 64; s > 0; s >>= 1) {
    if (t < s) red[t] = fmaxf(red[t], red[t + s]);
    __syncthreads();
  }
  float mx = red[0];
  __syncthreads();
  float e = expf(v - mx);
  red[t] = e;
  __syncthreads();
  for (int s = 64; s > 0; s >>= 1) {
    if (t < s) red[t] += red[t + s];
    __syncthreads();
  }
  S[row * 128 + t] = e / red[0];
}

// ---------------- depthwise 3x3 for V path (fp32 in, bf16 out) -------------
__global__ __launch_bounds__(256) void k_dw(const float* __restrict__ Y,
                                            const float* __restrict__ Kw,
                                            const float* __restrict__ db,
                                            bf16* __restrict__ Z) {
  const int c = blockIdx.y, bl = blockIdx.z;
  const int p = blockIdx.x * 256 + threadIdx.x;
  const int h = p >> 7, w = p & 127;
  const float* yp = Y + ((size_t)bl << 21) + ((size_t)c << 14);
  const float* kp = Kw + c * 9;
  float acc = db[c];
#pragma unroll
  for (int dy = -1; dy <= 1; ++dy) {
    int hh = h + dy;
    if (hh < 0 || hh >= 128) continue;
#pragma unroll
    for (int dx = -1; dx <= 1; ++dx) {
      int ww = w + dx;
      if (ww < 0 || ww >= 128) continue;
      acc += yp[hh * 128 + ww] * kp[(dy + 1) * 3 + (dx + 1)];
    }
  }
  Z[((size_t)bl << 21) + ((size_t)c << 14) + p] = __float2bfloat16(acc);
}

// ---------------- O[bl,c,n] = sum_d A[bl,c,d] * V[bl,d,n]  (bf16 out) ------
__global__ __launch_bounds__(256) void k_av(const float* __restrict__ A,
                                            const bf16* __restrict__ V,
                                            bf16* __restrict__ O) {
  __shared__ __align__(16) float As[32][128];
  __shared__ __align__(16) float Bs[32][128];
  const int bl = blockIdx.y;
  const int p0 = blockIdx.x * 128;
  const int t = threadIdx.x;
  const int m0 = (t >> 4) * 8, n0 = (t & 15) * 8;
  float acc[8][8];
#pragma unroll
  for (int i = 0; i < 8; ++i)
#pragma unroll
    for (int j = 0; j < 8; ++j) acc[i][j] = 0.f;
  const float* Ab = A + ((size_t)bl << 14);
  const bf16* Vb = V + ((size_t)bl << 21);
  const int am = t >> 1, ak = (t & 1) * 16;
  const int bk = t >> 3, bn = (t & 7) * 16;
  for (int k0 = 0; k0 < 128; k0 += 32) {
    const float* apg = Ab + am * 128 + k0 + ak;
#pragma unroll
    for (int j = 0; j < 16; ++j) As[ak + j][am] = apg[j];
    const bf16* vp = Vb + ((size_t)(k0 + bk) << 14) + p0 + bn;
#pragma unroll
    for (int j = 0; j < 16; ++j) Bs[bk][bn + j] = __bfloat162float(vp[j]);
    __syncthreads();
#pragma unroll
    for (int k = 0; k < 32; ++k) {
      const float4* ap = reinterpret_cast<const float4*>(&As[k][m0]);
      const float4* bp = reinterpret_cast<const float4*>(&Bs[k][n0]);
      float4 a0 = ap[0], a1 = ap[1];
      float4 b0v = bp[0], b1v = bp[1];
      float a[8] = {a0.x, a0.y, a0.z, a0.w, a1.x, a1.y, a1.z, a1.w};
      float bb[8] = {b0v.x, b0v.y, b0v.z, b0v.w, b1v.x, b1v.y, b1v.z, b1v.w};
#pragma unroll
      for (int i = 0; i < 8; ++i)
#pragma unroll
        for (int j = 0; j < 8; ++j) acc[i][j] = fmaf(a[i], bb[j], acc[i][j]);
    }
    __syncthreads();
  }
  bf16* Ob = O + ((size_t)bl << 21);
#pragma unroll
  for (int i = 0; i < 8; ++i) {
    bf16* op = Ob + ((size_t)(m0 + i) << 14) + p0 + n0;
#pragma unroll
    for (int j = 0; j < 8; ++j) op[j] = __float2bfloat16(acc[i][j]);
  }
}

// ---------------- final linear + residual (two accumulation passes) --------
// pass 0: out[b,c2,h2,w2] = sum_k Aw[bl,w2,c2*128+k]*lw[h2,k] + lb[h2]+Fi+Fw
// pass 1: out[b,c2,h2,w2] += sum_k Ai[bl,w2,c2*128+k]*lw[h2,128+k]
__global__ __launch_bounds__(256) void k_final(
    const bf16* __restrict__ Abuf, const float* __restrict__ lw,
    const float* __restrict__ lb, const float* __restrict__ Fi,
    const float* __restrict__ Fw, float* __restrict__ out, int pass, int b0) {
  __shared__ __align__(16) float As[32][128];
  __shared__ __align__(16) float Bs[32][128];
  const int c2 = blockIdx.x;
  const int bl = blockIdx.y;
  const int b = b0 + bl;
  const int t = threadIdx.x;
  const int m0 = (t >> 4) * 8, n0 = (t & 15) * 8;
  float acc[8][8];
#pragma unroll
  for (int i = 0; i < 8; ++i)
#pragma unroll
    for (int j = 0; j < 8; ++j) acc[i][j] = 0.f;
  const int am = t >> 1, ak = (t & 1) * 16;
  const int bn = t >> 1, bkk = (t & 1) * 16;
  const int koff = pass * 128;
  const size_t cbase = ((size_t)bl << 21) + (size_t)c2 * 128;
  for (int k0 = 0; k0 < 128; k0 += 32) {
    const float* lp = lw + am * 256 + koff + k0 + ak;
#pragma unroll
    for (int j = 0; j < 16; ++j) As[ak + j][am] = lp[j];
    const bf16* src = Abuf + cbase + ((size_t)bn << 14) + k0 + bkk;
#pragma unroll
    for (int j = 0; j < 16; ++j) Bs[bkk + j][bn] = __bfloat162float(src[j]);
    __syncthreads();
#pragma unroll
    for (int k = 0; k < 32; ++k) {
      const float4* ap = reinterpret_cast<const float4*>(&As[k][m0]);
      const float4* bp = reinterpret_cast<const float4*>(&Bs[k][n0]);
      float4 a0 = ap[0], a1 = ap[1];
      float4 b0v = bp[0], b1v = bp[1];
      float a[8] = {a0.x, a0.y, a0.z, a0.w, a1.x, a1.y, a1.z, a1.w};
      float bb[8] = {b0v.x, b0v.y, b0v.z, b0v.w, b1v.x, b1v.y, b1v.z, b1v.w};
#pragma unroll
      for (int i = 0; i < 8; ++i)
#pragma unroll
        for (int j = 0; j < 8; ++j) acc[i][j] = fmaf(a[i], bb[j], acc[i][j]);
    }
    __syncthreads();
  }
  const size_t obase = ((size_t)b << 21) + ((size_t)c2 << 14);
  if (pass == 0) {
#pragma unroll
    for (int i = 0; i < 8; ++i) {
      const int h2 = m0 + i;
      const float lbv = lb[h2];
#pragma unroll
      for (int j = 0; j < 8; ++j) {
        const size_t a = obase + (size_t)h2 * 128 + (n0 + j);
        out[a] = acc[i][j] + lbv + Fi[a] + Fw[a];
      }
    }
  } else {
#pragma unroll
    for (int i = 0; i < 8; ++i) {
      const int h2 = m0 + i;
#pragma unroll
      for (int j = 0; j < 8; ++j) {
        const size_t a = obase + (size_t)h2 * 128 + (n0 + j);
        out[a] += acc[i][j];
      }
    }
  }
}

extern "C" void kernel_launch(void* const* d_in, const int* in_sizes, int n_in,
                              void* d_out, int out_size, void* d_ws, size_t ws_size,
                              hipStream_t stream) {
  const float* F_i  = (const float*)d_in[0];
  const float* F_w  = (const float*)d_in[1];
  const float* g1   = (const float*)d_in[2];
  const float* g2   = (const float*)d_in[3];
  const float* qw1  = (const float*)d_in[4];
  const float* kw1  = (const float*)d_in[5];
  const float* vw1  = (const float*)d_in[6];
  const float* qw2  = (const float*)d_in[7];
  const float* kw2  = (const float*)d_in[8];
  const float* vw2  = (const float*)d_in[9];
  const float* qb1  = (const float*)d_in[10];
  const float* kb1  = (const float*)d_in[11];
  const float* vb1  = (const float*)d_in[12];
  const float* qb2  = (const float*)d_in[13];
  const float* kb2  = (const float*)d_in[14];
  const float* vb2  = (const float*)d_in[15];
  const float* qdw1 = (const float*)d_in[16];
  const float* kdw1 = (const float*)d_in[17];
  const float* vdw1 = (const float*)d_in[18];
  const float* qdw2 = (const float*)d_in[19];
  const float* kdw2 = (const float*)d_in[20];
  const float* vdw2 = (const float*)d_in[21];
  const float* qdb1 = (const float*)d_in[22];
  const float* kdb1 = (const float*)d_in[23];
  const float* vdb1 = (const float*)d_in[24];
  const float* qdb2 = (const float*)d_in[25];
  const float* kdb2 = (const float*)d_in[26];
  const float* vdb2 = (const float*)d_in[27];
  const float* lw   = (const float*)d_in[28];
  const float* lb   = (const float*)d_in[29];
  float* out = (float*)d_out;

  // ---- workspace (~82 MiB peak) ----
  char* w = (char*)d_ws;
  const size_t NTOT = (size_t)NB * HW;                     // 131072
  float* meanI = (float*)w; w += NTOT * 4;                 // 0.5 MiB
  float* rstdI = (float*)w; w += NTOT * 4;
  float* meanW = (float*)w; w += NTOT * 4;
  float* rstdW = (float*)w; w += NTOT * 4;
  float* S     = (float*)w; w += (size_t)GB * HW * 4;      // 0.25 MiB
  float* P     = (float*)w; w += (size_t)64 * GB * HW * 4; // 16 MiB
  float* Yq    = (float*)w; w += ((size_t)GB << 21) * 4;   // 32 MiB
  char*  Ykreg = w;         w += ((size_t)GB << 21) * 4;   // 32 MiB (overlaid)
  float* Yk    = (float*)Ykreg;                            // fp32 K-conv out
  bf16*  Vb    = (bf16*)Ykreg;                             // bf16 V (16 MiB)
  bf16*  Abuf  = (bf16*)(Ykreg + ((size_t)GB << 21) * 2);  // bf16 A (16 MiB)

  dim3 blk(256);
  k_ln_stats<<<dim3(512), blk, 0, stream>>>(F_i, meanI, rstdI);
  k_ln_stats<<<dim3(512), blk, 0, stream>>>(F_w, meanW, rstdW);

  for (int b0 = 0; b0 < NB; b0 += GB) {
    // ---- attention 1: a1 = softmax(Qi^T Kw) ; Aw = a1 @ Vw ; final pass 0 ----
    k_conv1x1_ln<<<dim3(128, GB), blk, 0, stream>>>(F_i, qw1, qb1, g1, meanI, rstdI, Yq, b0);
    k_conv1x1_ln<<<dim3(128, GB), blk, 0, stream>>>(F_w, kw2, kb2, g2, meanW, rstdW, Yk, b0);
    k_score_dw<<<dim3(64, GB), blk, 0, stream>>>(Yq, Yk, qdw1, qdb1, kdw2, kdb2, P);
    k_score_reduce<<<dim3(GB * HW / 256), blk, 0, stream>>>(P, S);
    k_softmax<<<dim3(GB * 128), dim3(128), 0, stream>>>(S);
    k_conv1x1_ln<<<dim3(128, GB), blk, 0, stream>>>(F_w, vw2, vb2, g2, meanW, rstdW, Yq, b0);
    k_dw<<<dim3(64, 128, GB), blk, 0, stream>>>(Yq, vdw2, vdb2, Vb);
    k_av<<<dim3(128, GB), blk, 0, stream>>>(S, Vb, Abuf);
    k_final<<<dim3(128, GB), blk, 0, stream>>>(Abuf, lw, lb, F_i, F_w, out, 0, b0);

    // ---- attention 2: a2 = softmax(Qw^T Ki) ; Ai = a2 @ Vi ; final pass 1 ----
    k_conv1x1_ln<<<dim3(128, GB), blk, 0, stream>>>(F_w, qw2, qb2, g2, meanW, rstdW, Yq, b0);
    k_conv1x1_ln<<<dim3(128, GB), blk, 0, stream>>>(F_i, kw1, kb1, g1, meanI, rstdI, Yk, b0);
    k_score_dw<<<dim3(64, GB), blk, 0, stream>>>(Yq, Yk, qdw2, qdb2, kdw1, kdb1, P);
    k_score_reduce<<<dim3(GB * HW / 256), blk, 0, stream>>>(P, S);
    k_softmax<<<dim3(GB * 128), dim3(128), 0, stream>>>(S);
    k_conv1x1_ln<<<dim3(128, GB), blk, 0, stream>>>(F_i, vw1, vb1, g1, meanI, rstdI, Yq, b0);
    k_dw<<<dim3(64, 128, GB), blk, 0, stream>>>(Yq, vdw1, vdb1, Vb);
    k_av<<<dim3(128, GB), blk, 0, stream>>>(S, Vb, Abuf);
    k_final<<<dim3(128, GB), blk, 0, stream>>>(Abuf, lw, lb, F_i, F_w, out, 1, b0);
  }
}

// Round 5
// 1172.247 us; speedup vs baseline: 1.2227x; 1.2227x over previous
//
#include <hip/hip_runtime.h>
#include <cstddef>
#include <cstring>

#define HW 16384
#define CC 128
#define NB 8
#define GB 4   // batches per group

typedef short bf16x8_t __attribute__((ext_vector_type(8)));
typedef float floatx4 __attribute__((ext_vector_type(4)));

__device__ inline unsigned short f2bf(float f) {
  unsigned u; __builtin_memcpy(&u, &f, 4);
  u += 0x7fffu + ((u >> 16) & 1u);
  return (unsigned short)(u >> 16);
}

// ---------------- LayerNorm stats (mean / rstd per (b,p)), all 8 batches ----
__global__ __launch_bounds__(256) void k_ln_stats(const float* __restrict__ x,
                                                  float* __restrict__ mean,
                                                  float* __restrict__ rstd) {
  int idx = blockIdx.x * 256 + threadIdx.x;   // 0 .. 131071
  int b = idx >> 14;
  int p = idx & (HW - 1);
  const float* xp = x + ((size_t)b << 21) + p;
  float s = 0.f, ss = 0.f;
  for (int c = 0; c < CC; ++c) {
    float v = xp[(size_t)c << 14];
    s += v;
    ss += v * v;
  }
  float m = s * (1.0f / CC);
  float var = ss * (1.0f / CC) - m * m;
  mean[idx] = m;
  rstd[idx] = rsqrtf(var + 1e-5f);
}

// ---------------- fused LN + 1x1 conv -> fp32 out (group-local batches) -----
__global__ __launch_bounds__(256) void k_conv1x1_ln(
    const float* __restrict__ X, const float* __restrict__ W,
    const float* __restrict__ bias, const float* __restrict__ g,
    const float* __restrict__ mean, const float* __restrict__ rstd,
    float* __restrict__ Y, int b0) {
  __shared__ __align__(16) float As[32][128];
  __shared__ __align__(16) float Bs[32][128];
  const int bl = blockIdx.y;
  const int b = b0 + bl;
  const int p0 = blockIdx.x * 128;
  const int t = threadIdx.x;
  const int m0 = (t >> 4) * 8;
  const int n0 = (t & 15) * 8;
  float acc[8][8];
  float sA[8];
#pragma unroll
  for (int i = 0; i < 8; ++i) {
    sA[i] = 0.f;
#pragma unroll
    for (int j = 0; j < 8; ++j) acc[i][j] = 0.f;
  }
  const float* Xb = X + ((size_t)b << 21);
  const int am = t >> 1, ak = (t & 1) * 16;
  const int bk = t >> 3, bn = (t & 7) * 16;
  for (int k0 = 0; k0 < 128; k0 += 32) {
    const float* wp = W + am * 128 + k0 + ak;
    const float* gp = g + k0 + ak;
#pragma unroll
    for (int j = 0; j < 16; ++j) As[ak + j][am] = wp[j] * gp[j];
    const float* xp = Xb + ((size_t)(k0 + bk) << 14) + p0 + bn;
#pragma unroll
    for (int j = 0; j < 16; ++j) Bs[bk][bn + j] = xp[j];
    __syncthreads();
#pragma unroll
    for (int k = 0; k < 32; ++k) {
      const float4* ap = reinterpret_cast<const float4*>(&As[k][m0]);
      const float4* bp = reinterpret_cast<const float4*>(&Bs[k][n0]);
      float4 a0 = ap[0], a1 = ap[1];
      float4 b0v = bp[0], b1v = bp[1];
      float a[8] = {a0.x, a0.y, a0.z, a0.w, a1.x, a1.y, a1.z, a1.w};
      float bb[8] = {b0v.x, b0v.y, b0v.z, b0v.w, b1v.x, b1v.y, b1v.z, b1v.w};
#pragma unroll
      for (int i = 0; i < 8; ++i) {
        sA[i] += a[i];
#pragma unroll
        for (int j = 0; j < 8; ++j) acc[i][j] = fmaf(a[i], bb[j], acc[i][j]);
      }
    }
    __syncthreads();
  }
  const int pb = b * HW + p0 + n0;
  float mu[8], rs[8];
#pragma unroll
  for (int j = 0; j < 8; ++j) { mu[j] = mean[pb + j]; rs[j] = rstd[pb + j]; }
  float* Yb = Y + ((size_t)bl << 21);
#pragma unroll
  for (int i = 0; i < 8; ++i) {
    const int o = m0 + i;
    const float bo = bias[o];
    float* yp = Yb + ((size_t)o << 14) + p0 + n0;
#pragma unroll
    for (int j = 0; j < 8; ++j)
      yp[j] = rs[j] * acc[i][j] - mu[j] * rs[j] * sA[i] + bo;
  }
}

// ---------------- score GEMM with depthwise-3x3 fused into LDS staging -------
// 128 chunks of 128 view-rows (one channel each): cc = ch, h = k0 + h_loc
__global__ __launch_bounds__(256) void k_score_dw(
    const float* __restrict__ Yq, const float* __restrict__ Yk,
    const float* __restrict__ qdw, const float* __restrict__ qdb,
    const float* __restrict__ kdw, const float* __restrict__ kdb,
    float* __restrict__ P) {
  __shared__ __align__(16) float As[32][132];
  __shared__ __align__(16) float Bs[32][132];
  const int ch = blockIdx.x;   // 128 chunks of 128 view-rows
  const int bl = blockIdx.y;
  const int t = threadIdx.x;
  const int m0 = (t >> 4) * 8, n0 = (t & 15) * 8;
  const int h_loc = t >> 3;
  const int w0 = (t & 7) * 16;
  float acc[8][8];
#pragma unroll
  for (int i = 0; i < 8; ++i)
#pragma unroll
    for (int j = 0; j < 8; ++j) acc[i][j] = 0.f;
  const float* Yqb = Yq + ((size_t)bl << 21);
  const float* Ykb = Yk + ((size_t)bl << 21);
  const int cc = ch;

  for (int k0 = 0; k0 < 128; k0 += 32) {
    const int h = k0 + h_loc;
#pragma unroll
    for (int side = 0; side < 2; ++side) {
      const float* Yc = (side ? Ykb : Yqb) + ((size_t)cc << 14);
      const float* wt = (side ? kdw : qdw) + cc * 9;
      const float bias = (side ? kdb : qdb)[cc];
      float a[16];
#pragma unroll
      for (int j = 0; j < 16; ++j) a[j] = bias;
#pragma unroll
      for (int dy = 0; dy < 3; ++dy) {
        const int hh = h + dy - 1;
        if (hh < 0 || hh > 127) continue;
        const float* rp = Yc + (hh << 7) + w0;
        float4 f0 = *reinterpret_cast<const float4*>(rp);
        float4 f1 = *reinterpret_cast<const float4*>(rp + 4);
        float4 f2 = *reinterpret_cast<const float4*>(rp + 8);
        float4 f3 = *reinterpret_cast<const float4*>(rp + 12);
        float s[18];
        s[1] = f0.x;  s[2] = f0.y;  s[3] = f0.z;  s[4] = f0.w;
        s[5] = f1.x;  s[6] = f1.y;  s[7] = f1.z;  s[8] = f1.w;
        s[9] = f2.x;  s[10] = f2.y; s[11] = f2.z; s[12] = f2.w;
        s[13] = f3.x; s[14] = f3.y; s[15] = f3.z; s[16] = f3.w;
        s[0] = (w0 > 0) ? rp[-1] : 0.f;
        s[17] = (w0 < 112) ? rp[16] : 0.f;
        const float wa = wt[dy * 3 + 0], wb = wt[dy * 3 + 1], wc2 = wt[dy * 3 + 2];
#pragma unroll
        for (int j = 0; j < 16; ++j)
          a[j] = fmaf(s[j], wa, fmaf(s[j + 1], wb, fmaf(s[j + 2], wc2, a[j])));
      }
      float* dst = side ? &Bs[h_loc][w0] : &As[h_loc][w0];
#pragma unroll
      for (int j = 0; j < 16; ++j) dst[j] = a[j];
    }
    __syncthreads();
#pragma unroll
    for (int k = 0; k < 32; ++k) {
      const float4* ap = reinterpret_cast<const float4*>(&As[k][m0]);
      const float4* bp = reinterpret_cast<const float4*>(&Bs[k][n0]);
      float4 a0 = ap[0], a1 = ap[1];
      float4 b0v = bp[0], b1v = bp[1];
      float a[8] = {a0.x, a0.y, a0.z, a0.w, a1.x, a1.y, a1.z, a1.w};
      float bb[8] = {b0v.x, b0v.y, b0v.z, b0v.w, b1v.x, b1v.y, b1v.z, b1v.w};
#pragma unroll
      for (int i = 0; i < 8; ++i)
#pragma unroll
        for (int j = 0; j < 8; ++j) acc[i][j] = fmaf(a[i], bb[j], acc[i][j]);
    }
    __syncthreads();
  }
  float* Pp = P + ((size_t)(ch * GB + bl) << 14);
#pragma unroll
  for (int i = 0; i < 8; ++i)
#pragma unroll
    for (int j = 0; j < 8; ++j) Pp[(m0 + i) * 128 + n0 + j] = acc[i][j];
}

// ---------------- reduce split-K partials -> S (GB batches) ----------------
__global__ __launch_bounds__(256) void k_score_reduce(const float* __restrict__ P,
                                                      float* __restrict__ S) {
  int idx = blockIdx.x * 256 + threadIdx.x;
  int bl = idx >> 14;
  int rem = idx & 16383;
  float s = 0.f;
  for (int c = 0; c < 128; ++c) s += P[((size_t)(c * GB + bl) << 14) + rem];
  S[idx] = s;
}

// ---------------- softmax over rows of 128 ----------------
__global__ __launch_bounds__(128) void k_softmax(float* __restrict__ S) {
  __shared__ float red[128];
  const int row = blockIdx.x;
  const int t = threadIdx.x;
  float v = S[row * 128 + t];
  red[t] = v;
  __syncthreads();
  for (int s = 64; s > 0; s >>= 1) {
    if (t < s) red[t] = fmaxf(red[t], red[t + s]);
    __syncthreads();
  }
  float mx = red[0];
  __syncthreads();
  float e = expf(v - mx);
  red[t] = e;
  __syncthreads();
  for (int s = 64; s > 0; s >>= 1) {
    if (t < s) red[t] += red[t + s];
    __syncthreads();
  }
  S[row * 128 + t] = e / red[0];
}

// ---------------- depthwise 3x3 + transpose: Vt[p][c] bf16 -----------------
// grid (128 h, 4 c-tiles, GB). Vt row p holds 128 channels contiguous.
__global__ __launch_bounds__(256) void k_dw_t(const float* __restrict__ Y,
                                              const float* __restrict__ Kw,
                                              const float* __restrict__ db,
                                              unsigned short* __restrict__ Vt) {
  __shared__ unsigned short T[128][33];
  const int h = blockIdx.x;
  const int c0 = blockIdx.y * 32;
  const int bl = blockIdx.z;
  const int t = threadIdx.x;
  const int cl = t >> 3;          // 0..31 local channel
  const int w0 = (t & 7) * 16;    // 16 pixels per thread
  const int c = c0 + cl;
  const float* Yc = Y + ((size_t)bl << 21) + ((size_t)c << 14);
  const float* wt = Kw + c * 9;
  float a[16];
#pragma unroll
  for (int j = 0; j < 16; ++j) a[j] = db[c];
#pragma unroll
  for (int dy = 0; dy < 3; ++dy) {
    const int hh = h + dy - 1;
    if (hh < 0 || hh > 127) continue;
    const float* rp = Yc + (hh << 7) + w0;
    float4 f0 = *reinterpret_cast<const float4*>(rp);
    float4 f1 = *reinterpret_cast<const float4*>(rp + 4);
    float4 f2 = *reinterpret_cast<const float4*>(rp + 8);
    float4 f3 = *reinterpret_cast<const float4*>(rp + 12);
    float s[18];
    s[1] = f0.x;  s[2] = f0.y;  s[3] = f0.z;  s[4] = f0.w;
    s[5] = f1.x;  s[6] = f1.y;  s[7] = f1.z;  s[8] = f1.w;
    s[9] = f2.x;  s[10] = f2.y; s[11] = f2.z; s[12] = f2.w;
    s[13] = f3.x; s[14] = f3.y; s[15] = f3.z; s[16] = f3.w;
    s[0] = (w0 > 0) ? rp[-1] : 0.f;
    s[17] = (w0 < 112) ? rp[16] : 0.f;
    const float wa = wt[dy * 3 + 0], wb = wt[dy * 3 + 1], wc2 = wt[dy * 3 + 2];
#pragma unroll
    for (int j = 0; j < 16; ++j)
      a[j] = fmaf(s[j], wa, fmaf(s[j + 1], wb, fmaf(s[j + 2], wc2, a[j])));
  }
#pragma unroll
  for (int j = 0; j < 16; ++j) T[w0 + j][cl] = f2bf(a[j]);
  __syncthreads();
  // writeout: thread t -> pixel w = t>>1, 16 channels starting at half*16.
  // 16 shorts = 32 bytes = TWO uint4 stores (round-4 bug: single uint4 only
  // wrote 8 of 16 channels, leaving uninitialized Vt -> NaN via MFMA).
  const int w = t >> 1, half = t & 1;
  unsigned short tmp[16];
#pragma unroll
  for (int j = 0; j < 16; ++j) tmp[j] = T[w][half * 16 + j];
  uint4 v0, v1;
  unsigned* vp0 = reinterpret_cast<unsigned*>(&v0);
  unsigned* vp1 = reinterpret_cast<unsigned*>(&v1);
#pragma unroll
  for (int j = 0; j < 4; ++j) {
    vp0[j] = (unsigned)tmp[2 * j] | ((unsigned)tmp[2 * j + 1] << 16);
    vp1[j] = (unsigned)tmp[8 + 2 * j] | ((unsigned)tmp[8 + 2 * j + 1] << 16);
  }
  unsigned short* dst = Vt + ((size_t)bl << 21) + ((size_t)((h << 7) + w) << 7)
                        + c0 + half * 16;
  *reinterpret_cast<uint4*>(dst) = v0;
  *reinterpret_cast<uint4*>(dst + 8) = v1;
}

// ---------------- MFMA: O[c,p] = sum_d Att[c,d] * V[d,p], Vt layout --------
// block 256 = 4 waves (2x2), tile 128x128, grid (128 p-tiles, GB)
__global__ __launch_bounds__(256) void k_av_mfma(
    const float* __restrict__ S, const unsigned short* __restrict__ Vt,
    unsigned short* __restrict__ O) {
  __shared__ __align__(16) short As[128][136];
  const int bl = blockIdx.y;
  const int p0 = blockIdx.x * 128;
  const int t = threadIdx.x;
  const int lane = t & 63, wv = t >> 6;
  const int quad = lane >> 4, l15 = lane & 15;
  const int wr = wv >> 1, wc = wv & 1;
  // stage Att (fp32 -> bf16) into LDS
  {
    const float* Ab = S + ((size_t)bl << 14);
    const int r = t >> 1, hf = (t & 1) * 64;
    const float* src = Ab + r * 128 + hf;
    short tmp[64];
#pragma unroll
    for (int j = 0; j < 64; ++j) tmp[j] = (short)f2bf(src[j]);
#pragma unroll
    for (int j = 0; j < 8; ++j)
      *reinterpret_cast<bf16x8_t*>(&As[r][hf + j * 8]) =
          *reinterpret_cast<bf16x8_t*>(&tmp[j * 8]);
  }
  __syncthreads();
  floatx4 acc[4][4];
#pragma unroll
  for (int i = 0; i < 4; ++i)
#pragma unroll
    for (int j = 0; j < 4; ++j) acc[i][j] = (floatx4){0.f, 0.f, 0.f, 0.f};
  const unsigned short* Vb = Vt + ((size_t)bl << 21);
#pragma unroll
  for (int d0 = 0; d0 < 128; d0 += 32) {
    bf16x8_t af[4], bf[4];
#pragma unroll
    for (int i = 0; i < 4; ++i) {
      const int m = wr * 64 + i * 16 + l15;
      af[i] = *reinterpret_cast<const bf16x8_t*>(&As[m][d0 + quad * 8]);
    }
#pragma unroll
    for (int j = 0; j < 4; ++j) {
      const int p = p0 + wc * 64 + j * 16 + l15;
      bf[j] = *reinterpret_cast<const bf16x8_t*>(Vb + ((size_t)p << 7) + d0 + quad * 8);
    }
#pragma unroll
    for (int i = 0; i < 4; ++i)
#pragma unroll
      for (int j = 0; j < 4; ++j)
        acc[i][j] = __builtin_amdgcn_mfma_f32_16x16x32_bf16(af[i], bf[j], acc[i][j], 0, 0, 0);
  }
  unsigned short* Ob = O + ((size_t)bl << 21);
#pragma unroll
  for (int i = 0; i < 4; ++i) {
#pragma unroll
    for (int j = 0; j < 4; ++j) {
#pragma unroll
      for (int r = 0; r < 4; ++r) {
        const int c = wr * 64 + i * 16 + quad * 4 + r;
        const int p = p0 + wc * 64 + j * 16 + l15;
        Ob[((size_t)c << 14) + p] = f2bf(acc[i][j][r]);
      }
    }
  }
}

// ---------------- MFMA final linear + residual (two passes) ----------------
// pass0: out = lw[:, :128] . U + lb + Fi + Fw ; pass1: out += lw[:,128:] . U
// U[k][n] = Abuf[bl, n, c2*128 + k]  (k-contiguous in Abuf rows)
__global__ __launch_bounds__(256) void k_final_mfma(
    const unsigned short* __restrict__ Abuf, const float* __restrict__ lw,
    const float* __restrict__ lb, const float* __restrict__ Fi,
    const float* __restrict__ Fw, float* __restrict__ out, int pass, int b0) {
  __shared__ __align__(16) short As[128][136];
  const int c2 = blockIdx.x;
  const int bl = blockIdx.y;
  const int b = b0 + bl;
  const int t = threadIdx.x;
  const int lane = t & 63, wv = t >> 6;
  const int quad = lane >> 4, l15 = lane & 15;
  const int wr = wv >> 1, wc = wv & 1;
  const int koff = pass * 128;
  {
    const int r = t >> 1, hf = (t & 1) * 64;
    const float* src = lw + r * 256 + koff + hf;
    short tmp[64];
#pragma unroll
    for (int j = 0; j < 64; ++j) tmp[j] = (short)f2bf(src[j]);
#pragma unroll
    for (int j = 0; j < 8; ++j)
      *reinterpret_cast<bf16x8_t*>(&As[r][hf + j * 8]) =
          *reinterpret_cast<bf16x8_t*>(&tmp[j * 8]);
  }
  __syncthreads();
  floatx4 acc[4][4];
#pragma unroll
  for (int i = 0; i < 4; ++i)
#pragma unroll
    for (int j = 0; j < 4; ++j) acc[i][j] = (floatx4){0.f, 0.f, 0.f, 0.f};
  const unsigned short* Ub = Abuf + ((size_t)bl << 21) + c2 * 128;
#pragma unroll
  for (int d0 = 0; d0 < 128; d0 += 32) {
    bf16x8_t af[4], bf[4];
#pragma unroll
    for (int i = 0; i < 4; ++i) {
      const int m = wr * 64 + i * 16 + l15;
      af[i] = *reinterpret_cast<const bf16x8_t*>(&As[m][d0 + quad * 8]);
    }
#pragma unroll
    for (int j = 0; j < 4; ++j) {
      const int n = wc * 64 + j * 16 + l15;
      bf[j] = *reinterpret_cast<const bf16x8_t*>(Ub + ((size_t)n << 14) + d0 + quad * 8);
    }
#pragma unroll
    for (int i = 0; i < 4; ++i)
#pragma unroll
      for (int j = 0; j < 4; ++j)
        acc[i][j] = __builtin_amdgcn_mfma_f32_16x16x32_bf16(af[i], bf[j], acc[i][j], 0, 0, 0);
  }
  const size_t obase = ((size_t)b << 21) + ((size_t)c2 << 14);
#pragma unroll
  for (int i = 0; i < 4; ++i) {
#pragma unroll
    for (int j = 0; j < 4; ++j) {
#pragma unroll
      for (int r = 0; r < 4; ++r) {
        const int h2 = wr * 64 + i * 16 + quad * 4 + r;
        const int w2 = wc * 64 + j * 16 + l15;
        const size_t a = obase + ((size_t)h2 << 7) + w2;
        if (pass == 0)
          out[a] = acc[i][j][r] + lb[h2] + Fi[a] + Fw[a];
        else
          out[a] += acc[i][j][r];
      }
    }
  }
}

extern "C" void kernel_launch(void* const* d_in, const int* in_sizes, int n_in,
                              void* d_out, int out_size, void* d_ws, size_t ws_size,
                              hipStream_t stream) {
  const float* F_i  = (const float*)d_in[0];
  const float* F_w  = (const float*)d_in[1];
  const float* g1   = (const float*)d_in[2];
  const float* g2   = (const float*)d_in[3];
  const float* qw1  = (const float*)d_in[4];
  const float* kw1  = (const float*)d_in[5];
  const float* vw1  = (const float*)d_in[6];
  const float* qw2  = (const float*)d_in[7];
  const float* kw2  = (const float*)d_in[8];
  const float* vw2  = (const float*)d_in[9];
  const float* qb1  = (const float*)d_in[10];
  const float* kb1  = (const float*)d_in[11];
  const float* vb1  = (const float*)d_in[12];
  const float* qb2  = (const float*)d_in[13];
  const float* kb2  = (const float*)d_in[14];
  const float* vb2  = (const float*)d_in[15];
  const float* qdw1 = (const float*)d_in[16];
  const float* kdw1 = (const float*)d_in[17];
  const float* vdw1 = (const float*)d_in[18];
  const float* qdw2 = (const float*)d_in[19];
  const float* kdw2 = (const float*)d_in[20];
  const float* vdw2 = (const float*)d_in[21];
  const float* qdb1 = (const float*)d_in[22];
  const float* kdb1 = (const float*)d_in[23];
  const float* vdb1 = (const float*)d_in[24];
  const float* qdb2 = (const float*)d_in[25];
  const float* kdb2 = (const float*)d_in[26];
  const float* vdb2 = (const float*)d_in[27];
  const float* lw   = (const float*)d_in[28];
  const float* lb   = (const float*)d_in[29];
  float* out = (float*)d_out;

  // ---- workspace (~98 MiB peak) ----
  char* w = (char*)d_ws;
  const size_t NTOT = (size_t)NB * HW;                      // 131072
  float* meanI = (float*)w; w += NTOT * 4;
  float* rstdI = (float*)w; w += NTOT * 4;
  float* meanW = (float*)w; w += NTOT * 4;
  float* rstdW = (float*)w; w += NTOT * 4;
  float* S     = (float*)w; w += (size_t)GB * HW * 4;       // 0.25 MiB
  float* P     = (float*)w; w += (size_t)128 * GB * HW * 4; // 32 MiB
  float* Yq    = (float*)w; w += ((size_t)GB << 21) * 4;    // 32 MiB
  char*  Ykreg = w;         w += ((size_t)GB << 21) * 4;    // 32 MiB (overlaid)
  float* Yk    = (float*)Ykreg;                             // fp32 K-conv out
  unsigned short* Vt   = (unsigned short*)Ykreg;                          // 16 MiB
  unsigned short* Abuf = (unsigned short*)(Ykreg + ((size_t)GB << 21) * 2); // 16 MiB

  dim3 blk(256);
  k_ln_stats<<<dim3(512), blk, 0, stream>>>(F_i, meanI, rstdI);
  k_ln_stats<<<dim3(512), blk, 0, stream>>>(F_w, meanW, rstdW);

  for (int b0 = 0; b0 < NB; b0 += GB) {
    // ---- attention 1: a1 = softmax(Qi^T Kw) ; Aw = a1 @ Vw ; final pass 0 ----
    k_conv1x1_ln<<<dim3(128, GB), blk, 0, stream>>>(F_i, qw1, qb1, g1, meanI, rstdI, Yq, b0);
    k_conv1x1_ln<<<dim3(128, GB), blk, 0, stream>>>(F_w, kw2, kb2, g2, meanW, rstdW, Yk, b0);
    k_score_dw<<<dim3(128, GB), blk, 0, stream>>>(Yq, Yk, qdw1, qdb1, kdw2, kdb2, P);
    k_score_reduce<<<dim3(GB * HW / 256), blk, 0, stream>>>(P, S);
    k_softmax<<<dim3(GB * 128), dim3(128), 0, stream>>>(S);
    k_conv1x1_ln<<<dim3(128, GB), blk, 0, stream>>>(F_w, vw2, vb2, g2, meanW, rstdW, Yq, b0);
    k_dw_t<<<dim3(128, 4, GB), blk, 0, stream>>>(Yq, vdw2, vdb2, Vt);
    k_av_mfma<<<dim3(128, GB), blk, 0, stream>>>(S, Vt, Abuf);
    k_final_mfma<<<dim3(128, GB), blk, 0, stream>>>(Abuf, lw, lb, F_i, F_w, out, 0, b0);

    // ---- attention 2: a2 = softmax(Qw^T Ki) ; Ai = a2 @ Vi ; final pass 1 ----
    k_conv1x1_ln<<<dim3(128, GB), blk, 0, stream>>>(F_w, qw2, qb2, g2, meanW, rstdW, Yq, b0);
    k_conv1x1_ln<<<dim3(128, GB), blk, 0, stream>>>(F_i, kw1, kb1, g1, meanI, rstdI, Yk, b0);
    k_score_dw<<<dim3(128, GB), blk, 0, stream>>>(Yq, Yk, qdw2, qdb2, kdw1, kdb1, P);
    k_score_reduce<<<dim3(GB * HW / 256), blk, 0, stream>>>(P, S);
    k_softmax<<<dim3(GB * 128), dim3(128), 0, stream>>>(S);
    k_conv1x1_ln<<<dim3(128, GB), blk, 0, stream>>>(F_i, vw1, vb1, g1, meanI, rstdI, Yq, b0);
    k_dw_t<<<dim3(128, 4, GB), blk, 0, stream>>>(Yq, vdw1, vdb1, Vt);
    k_av_mfma<<<dim3(128, GB), blk, 0, stream>>>(S, Vt, Abuf);
    k_final_mfma<<<dim3(128, GB), blk, 0, stream>>>(Abuf, lw, lb, F_i, F_w, out, 1, b0);
  }
}

// Round 6
// 922.045 us; speedup vs baseline: 1.5545x; 1.2714x over previous
//
#include <hip/hip_runtime.h>
#include <cstddef>
#include <cstring>

#define HW 16384
#define CC 128
#define NB 8
#define GB 4   // batches per group

typedef short bf16x8_t __attribute__((ext_vector_type(8)));
typedef float floatx4 __attribute__((ext_vector_type(4)));

__device__ inline unsigned short f2bf(float f) {
  unsigned u; __builtin_memcpy(&u, &f, 4);
  u += 0x7fffu + ((u >> 16) & 1u);
  return (unsigned short)(u >> 16);
}
__device__ inline float bf2f(unsigned short s) {
  unsigned u = ((unsigned)s) << 16; float f; __builtin_memcpy(&f, &u, 4);
  return f;
}

// ---------------- LayerNorm stats (mean / rstd per (b,p)), all 8 batches ----
__global__ __launch_bounds__(256) void k_ln_stats(const float* __restrict__ x,
                                                  float* __restrict__ mean,
                                                  float* __restrict__ rstd) {
  int idx = blockIdx.x * 256 + threadIdx.x;   // 0 .. 131071
  int b = idx >> 14;
  int p = idx & (HW - 1);
  const float* xp = x + ((size_t)b << 21) + p;
  float s = 0.f, ss = 0.f;
  for (int c = 0; c < CC; ++c) {
    float v = xp[(size_t)c << 14];
    s += v;
    ss += v * v;
  }
  float m = s * (1.0f / CC);
  float var = ss * (1.0f / CC) - m * m;
  mean[idx] = m;
  rstd[idx] = rsqrtf(var + 1e-5f);
}

// ---------------- split-bf16 MFMA LN+1x1 conv ----------------
// Y[o,p] = sum_c (W[o,c]*g[c]) * (X[c,p]-mu_p)*r_p + bias[o]
// 3 MFMA passes hi*hi + hi*lo + lo*hi  => ~fp32 accuracy (err ~2^-18).
__global__ __launch_bounds__(256) void k_conv1x1_mfma(
    const float* __restrict__ X, const float* __restrict__ W,
    const float* __restrict__ bias, const float* __restrict__ g,
    const float* __restrict__ mean, const float* __restrict__ rstd,
    float* __restrict__ Y, int b0) {
  __shared__ __align__(16) float raw[32][132];   // X chunk [c][p]
  __shared__ __align__(16) short Ah[128][40];    // Wg hi [o][c_local]
  __shared__ __align__(16) short Al[128][40];
  __shared__ __align__(16) short Bh[128][40];    // Xn hi [p][c_local]
  __shared__ __align__(16) short Bl[128][40];
  const int bl = blockIdx.y;
  const int b = b0 + bl;
  const int p0 = blockIdx.x * 128;
  const int t = threadIdx.x;
  const int lane = t & 63, wv = t >> 6;
  const int quad = lane >> 4, l15 = lane & 15;
  const int wr = wv >> 1, wc = wv & 1;

  // stage-1 thread mapping (global->raw): c_l = t>>3, pseg = (t&7)*16
  const int s1c = t >> 3, s1p = (t & 7) * 16;
  // stage-A mapping (weights): o = t>>1, seg = (t&1)*16
  const int sao = t >> 1, sas = (t & 1) * 16;
  // stage-2 mapping (raw->Bh/Bl transposed): p = t&127, oct base = t>>7
  const int s2p = t & 127, s2o = t >> 7;
  const float mu = mean[b * HW + p0 + s2p];
  const float rs = rstd[b * HW + p0 + s2p];

  const float* Xb = X + ((size_t)b << 21);
  floatx4 acc[4][4];
#pragma unroll
  for (int i = 0; i < 4; ++i)
#pragma unroll
    for (int j = 0; j < 4; ++j) acc[i][j] = (floatx4){0.f, 0.f, 0.f, 0.f};

  for (int k0 = 0; k0 < 128; k0 += 32) {
    // ---- stage 1: X[c][p] chunk -> raw (coalesced) ----
    {
      const float* xp = Xb + ((size_t)(k0 + s1c) << 14) + p0 + s1p;
#pragma unroll
      for (int u = 0; u < 4; ++u)
        *reinterpret_cast<float4*>(&raw[s1c][s1p + 4 * u]) =
            *reinterpret_cast<const float4*>(xp + 4 * u);
    }
    // ---- stage A: weights*g -> hi/lo ----
    {
      const float* wp = W + sao * 128 + k0 + sas;
      const float* gp = g + k0 + sas;
      short th[16], tl[16];
#pragma unroll
      for (int j = 0; j < 16; ++j) {
        float v = wp[j] * gp[j];
        unsigned short h = f2bf(v);
        th[j] = (short)h;
        tl[j] = (short)f2bf(v - bf2f(h));
      }
#pragma unroll
      for (int j = 0; j < 2; ++j) {
        *reinterpret_cast<bf16x8_t*>(&Ah[sao][sas + 8 * j]) =
            *reinterpret_cast<bf16x8_t*>(&th[8 * j]);
        *reinterpret_cast<bf16x8_t*>(&Al[sao][sas + 8 * j]) =
            *reinterpret_cast<bf16x8_t*>(&tl[8 * j]);
      }
    }
    __syncthreads();
    // ---- stage 2: transpose + LN + hi/lo split ----
#pragma unroll
    for (int item = 0; item < 2; ++item) {
      const int oct = s2o + 2 * item;     // 0..3
      short th[8], tl[8];
#pragma unroll
      for (int jj = 0; jj < 8; ++jj) {
        float v = (raw[oct * 8 + jj][s2p] - mu) * rs;
        unsigned short h = f2bf(v);
        th[jj] = (short)h;
        tl[jj] = (short)f2bf(v - bf2f(h));
      }
      *reinterpret_cast<bf16x8_t*>(&Bh[s2p][oct * 8]) =
          *reinterpret_cast<bf16x8_t*>(&th[0]);
      *reinterpret_cast<bf16x8_t*>(&Bl[s2p][oct * 8]) =
          *reinterpret_cast<bf16x8_t*>(&tl[0]);
    }
    __syncthreads();
    // ---- MFMA: one K=32 step, 3 split passes ----
    bf16x8_t afh[4], afl[4], bfh[4], bfl[4];
#pragma unroll
    for (int i = 0; i < 4; ++i) {
      const int m = wr * 64 + i * 16 + l15;
      afh[i] = *reinterpret_cast<const bf16x8_t*>(&Ah[m][quad * 8]);
      afl[i] = *reinterpret_cast<const bf16x8_t*>(&Al[m][quad * 8]);
    }
#pragma unroll
    for (int j = 0; j < 4; ++j) {
      const int p = wc * 64 + j * 16 + l15;
      bfh[j] = *reinterpret_cast<const bf16x8_t*>(&Bh[p][quad * 8]);
      bfl[j] = *reinterpret_cast<const bf16x8_t*>(&Bl[p][quad * 8]);
    }
#pragma unroll
    for (int i = 0; i < 4; ++i)
#pragma unroll
      for (int j = 0; j < 4; ++j) {
        acc[i][j] = __builtin_amdgcn_mfma_f32_16x16x32_bf16(afh[i], bfh[j], acc[i][j], 0, 0, 0);
        acc[i][j] = __builtin_amdgcn_mfma_f32_16x16x32_bf16(afh[i], bfl[j], acc[i][j], 0, 0, 0);
        acc[i][j] = __builtin_amdgcn_mfma_f32_16x16x32_bf16(afl[i], bfh[j], acc[i][j], 0, 0, 0);
      }
    __syncthreads();
  }
  // ---- epilogue: + bias, store fp32 ----
  float* Yb = Y + ((size_t)bl << 21);
#pragma unroll
  for (int i = 0; i < 4; ++i) {
#pragma unroll
    for (int j = 0; j < 4; ++j) {
#pragma unroll
      for (int r = 0; r < 4; ++r) {
        const int o = wr * 64 + i * 16 + quad * 4 + r;
        const int p = p0 + wc * 64 + j * 16 + l15;
        Yb[((size_t)o << 14) + p] = acc[i][j][r] + bias[o];
      }
    }
  }
}

// ---------------- score GEMM with depthwise-3x3 fused into LDS staging -------
__global__ __launch_bounds__(256) void k_score_dw(
    const float* __restrict__ Yq, const float* __restrict__ Yk,
    const float* __restrict__ qdw, const float* __restrict__ qdb,
    const float* __restrict__ kdw, const float* __restrict__ kdb,
    float* __restrict__ P) {
  __shared__ __align__(16) float As[32][132];
  __shared__ __align__(16) float Bs[32][132];
  const int ch = blockIdx.x;   // 128 chunks of 128 view-rows
  const int bl = blockIdx.y;
  const int t = threadIdx.x;
  const int m0 = (t >> 4) * 8, n0 = (t & 15) * 8;
  const int h_loc = t >> 3;
  const int w0 = (t & 7) * 16;
  float acc[8][8];
#pragma unroll
  for (int i = 0; i < 8; ++i)
#pragma unroll
    for (int j = 0; j < 8; ++j) acc[i][j] = 0.f;
  const float* Yqb = Yq + ((size_t)bl << 21);
  const float* Ykb = Yk + ((size_t)bl << 21);
  const int cc = ch;

  for (int k0 = 0; k0 < 128; k0 += 32) {
    const int h = k0 + h_loc;
#pragma unroll
    for (int side = 0; side < 2; ++side) {
      const float* Yc = (side ? Ykb : Yqb) + ((size_t)cc << 14);
      const float* wt = (side ? kdw : qdw) + cc * 9;
      const float bias = (side ? kdb : qdb)[cc];
      float a[16];
#pragma unroll
      for (int j = 0; j < 16; ++j) a[j] = bias;
#pragma unroll
      for (int dy = 0; dy < 3; ++dy) {
        const int hh = h + dy - 1;
        if (hh < 0 || hh > 127) continue;
        const float* rp = Yc + (hh << 7) + w0;
        float4 f0 = *reinterpret_cast<const float4*>(rp);
        float4 f1 = *reinterpret_cast<const float4*>(rp + 4);
        float4 f2 = *reinterpret_cast<const float4*>(rp + 8);
        float4 f3 = *reinterpret_cast<const float4*>(rp + 12);
        float s[18];
        s[1] = f0.x;  s[2] = f0.y;  s[3] = f0.z;  s[4] = f0.w;
        s[5] = f1.x;  s[6] = f1.y;  s[7] = f1.z;  s[8] = f1.w;
        s[9] = f2.x;  s[10] = f2.y; s[11] = f2.z; s[12] = f2.w;
        s[13] = f3.x; s[14] = f3.y; s[15] = f3.z; s[16] = f3.w;
        s[0] = (w0 > 0) ? rp[-1] : 0.f;
        s[17] = (w0 < 112) ? rp[16] : 0.f;
        const float wa = wt[dy * 3 + 0], wb = wt[dy * 3 + 1], wc2 = wt[dy * 3 + 2];
#pragma unroll
        for (int j = 0; j < 16; ++j)
          a[j] = fmaf(s[j], wa, fmaf(s[j + 1], wb, fmaf(s[j + 2], wc2, a[j])));
      }
      float* dst = side ? &Bs[h_loc][w0] : &As[h_loc][w0];
#pragma unroll
      for (int j = 0; j < 16; ++j) dst[j] = a[j];
    }
    __syncthreads();
#pragma unroll
    for (int k = 0; k < 32; ++k) {
      const float4* ap = reinterpret_cast<const float4*>(&As[k][m0]);
      const float4* bp = reinterpret_cast<const float4*>(&Bs[k][n0]);
      float4 a0 = ap[0], a1 = ap[1];
      float4 b0v = bp[0], b1v = bp[1];
      float a[8] = {a0.x, a0.y, a0.z, a0.w, a1.x, a1.y, a1.z, a1.w};
      float bb[8] = {b0v.x, b0v.y, b0v.z, b0v.w, b1v.x, b1v.y, b1v.z, b1v.w};
#pragma unroll
      for (int i = 0; i < 8; ++i)
#pragma unroll
        for (int j = 0; j < 8; ++j) acc[i][j] = fmaf(a[i], bb[j], acc[i][j]);
    }
    __syncthreads();
  }
  float* Pp = P + ((size_t)(ch * GB + bl) << 14);
#pragma unroll
  for (int i = 0; i < 8; ++i)
#pragma unroll
    for (int j = 0; j < 8; ++j) Pp[(m0 + i) * 128 + n0 + j] = acc[i][j];
}

// ---------------- reduce split-K partials -> S (GB batches) ----------------
__global__ __launch_bounds__(256) void k_score_reduce(const float* __restrict__ P,
                                                      float* __restrict__ S) {
  int idx = blockIdx.x * 256 + threadIdx.x;
  int bl = idx >> 14;
  int rem = idx & 16383;
  float s = 0.f;
  for (int c = 0; c < 128; ++c) s += P[((size_t)(c * GB + bl) << 14) + rem];
  S[idx] = s;
}

// ---------------- softmax over rows of 128 ----------------
__global__ __launch_bounds__(128) void k_softmax(float* __restrict__ S) {
  __shared__ float red[128];
  const int row = blockIdx.x;
  const int t = threadIdx.x;
  float v = S[row * 128 + t];
  red[t] = v;
  __syncthreads();
  for (int s = 64; s > 0; s >>= 1) {
    if (t < s) red[t] = fmaxf(red[t], red[t + s]);
    __syncthreads();
  }
  float mx = red[0];
  __syncthreads();
  float e = expf(v - mx);
  red[t] = e;
  __syncthreads();
  for (int s = 64; s > 0; s >>= 1) {
    if (t < s) red[t] += red[t + s];
    __syncthreads();
  }
  S[row * 128 + t] = e / red[0];
}

// ---------------- depthwise 3x3 + transpose: Vt[p][c] bf16 -----------------
__global__ __launch_bounds__(256) void k_dw_t(const float* __restrict__ Y,
                                              const float* __restrict__ Kw,
                                              const float* __restrict__ db,
                                              unsigned short* __restrict__ Vt) {
  __shared__ unsigned short T[128][33];
  const int h = blockIdx.x;
  const int c0 = blockIdx.y * 32;
  const int bl = blockIdx.z;
  const int t = threadIdx.x;
  const int cl = t >> 3;
  const int w0 = (t & 7) * 16;
  const int c = c0 + cl;
  const float* Yc = Y + ((size_t)bl << 21) + ((size_t)c << 14);
  const float* wt = Kw + c * 9;
  float a[16];
#pragma unroll
  for (int j = 0; j < 16; ++j) a[j] = db[c];
#pragma unroll
  for (int dy = 0; dy < 3; ++dy) {
    const int hh = h + dy - 1;
    if (hh < 0 || hh > 127) continue;
    const float* rp = Yc + (hh << 7) + w0;
    float4 f0 = *reinterpret_cast<const float4*>(rp);
    float4 f1 = *reinterpret_cast<const float4*>(rp + 4);
    float4 f2 = *reinterpret_cast<const float4*>(rp + 8);
    float4 f3 = *reinterpret_cast<const float4*>(rp + 12);
    float s[18];
    s[1] = f0.x;  s[2] = f0.y;  s[3] = f0.z;  s[4] = f0.w;
    s[5] = f1.x;  s[6] = f1.y;  s[7] = f1.z;  s[8] = f1.w;
    s[9] = f2.x;  s[10] = f2.y; s[11] = f2.z; s[12] = f2.w;
    s[13] = f3.x; s[14] = f3.y; s[15] = f3.z; s[16] = f3.w;
    s[0] = (w0 > 0) ? rp[-1] : 0.f;
    s[17] = (w0 < 112) ? rp[16] : 0.f;
    const float wa = wt[dy * 3 + 0], wb = wt[dy * 3 + 1], wc2 = wt[dy * 3 + 2];
#pragma unroll
    for (int j = 0; j < 16; ++j)
      a[j] = fmaf(s[j], wa, fmaf(s[j + 1], wb, fmaf(s[j + 2], wc2, a[j])));
  }
#pragma unroll
  for (int j = 0; j < 16; ++j) T[w0 + j][cl] = f2bf(a[j]);
  __syncthreads();
  const int w = t >> 1, half = t & 1;
  unsigned short tmp[16];
#pragma unroll
  for (int j = 0; j < 16; ++j) tmp[j] = T[w][half * 16 + j];
  uint4 v0, v1;
  unsigned* vp0 = reinterpret_cast<unsigned*>(&v0);
  unsigned* vp1 = reinterpret_cast<unsigned*>(&v1);
#pragma unroll
  for (int j = 0; j < 4; ++j) {
    vp0[j] = (unsigned)tmp[2 * j] | ((unsigned)tmp[2 * j + 1] << 16);
    vp1[j] = (unsigned)tmp[8 + 2 * j] | ((unsigned)tmp[8 + 2 * j + 1] << 16);
  }
  unsigned short* dst = Vt + ((size_t)bl << 21) + ((size_t)((h << 7) + w) << 7)
                        + c0 + half * 16;
  *reinterpret_cast<uint4*>(dst) = v0;
  *reinterpret_cast<uint4*>(dst + 8) = v1;
}

// ---------------- MFMA: O[c,p] = sum_d Att[c,d] * V[d,p], Vt layout --------
__global__ __launch_bounds__(256) void k_av_mfma(
    const float* __restrict__ S, const unsigned short* __restrict__ Vt,
    unsigned short* __restrict__ O) {
  __shared__ __align__(16) short As[128][136];
  const int bl = blockIdx.y;
  const int p0 = blockIdx.x * 128;
  const int t = threadIdx.x;
  const int lane = t & 63, wv = t >> 6;
  const int quad = lane >> 4, l15 = lane & 15;
  const int wr = wv >> 1, wc = wv & 1;
  {
    const float* Ab = S + ((size_t)bl << 14);
    const int r = t >> 1, hf = (t & 1) * 64;
    const float* src = Ab + r * 128 + hf;
    short tmp[64];
#pragma unroll
    for (int j = 0; j < 64; ++j) tmp[j] = (short)f2bf(src[j]);
#pragma unroll
    for (int j = 0; j < 8; ++j)
      *reinterpret_cast<bf16x8_t*>(&As[r][hf + j * 8]) =
          *reinterpret_cast<bf16x8_t*>(&tmp[j * 8]);
  }
  __syncthreads();
  floatx4 acc[4][4];
#pragma unroll
  for (int i = 0; i < 4; ++i)
#pragma unroll
    for (int j = 0; j < 4; ++j) acc[i][j] = (floatx4){0.f, 0.f, 0.f, 0.f};
  const unsigned short* Vb = Vt + ((size_t)bl << 21);
#pragma unroll
  for (int d0 = 0; d0 < 128; d0 += 32) {
    bf16x8_t af[4], bf[4];
#pragma unroll
    for (int i = 0; i < 4; ++i) {
      const int m = wr * 64 + i * 16 + l15;
      af[i] = *reinterpret_cast<const bf16x8_t*>(&As[m][d0 + quad * 8]);
    }
#pragma unroll
    for (int j = 0; j < 4; ++j) {
      const int p = p0 + wc * 64 + j * 16 + l15;
      bf[j] = *reinterpret_cast<const bf16x8_t*>(Vb + ((size_t)p << 7) + d0 + quad * 8);
    }
#pragma unroll
    for (int i = 0; i < 4; ++i)
#pragma unroll
      for (int j = 0; j < 4; ++j)
        acc[i][j] = __builtin_amdgcn_mfma_f32_16x16x32_bf16(af[i], bf[j], acc[i][j], 0, 0, 0);
  }
  unsigned short* Ob = O + ((size_t)bl << 21);
#pragma unroll
  for (int i = 0; i < 4; ++i) {
#pragma unroll
    for (int j = 0; j < 4; ++j) {
#pragma unroll
      for (int r = 0; r < 4; ++r) {
        const int c = wr * 64 + i * 16 + quad * 4 + r;
        const int p = p0 + wc * 64 + j * 16 + l15;
        Ob[((size_t)c << 14) + p] = f2bf(acc[i][j][r]);
      }
    }
  }
}

// ---------------- MFMA final linear + residual (two passes) ----------------
__global__ __launch_bounds__(256) void k_final_mfma(
    const unsigned short* __restrict__ Abuf, const float* __restrict__ lw,
    const float* __restrict__ lb, const float* __restrict__ Fi,
    const float* __restrict__ Fw, float* __restrict__ out, int pass, int b0) {
  __shared__ __align__(16) short As[128][136];
  const int c2 = blockIdx.x;
  const int bl = blockIdx.y;
  const int b = b0 + bl;
  const int t = threadIdx.x;
  const int lane = t & 63, wv = t >> 6;
  const int quad = lane >> 4, l15 = lane & 15;
  const int wr = wv >> 1, wc = wv & 1;
  const int koff = pass * 128;
  {
    const int r = t >> 1, hf = (t & 1) * 64;
    const float* src = lw + r * 256 + koff + hf;
    short tmp[64];
#pragma unroll
    for (int j = 0; j < 64; ++j) tmp[j] = (short)f2bf(src[j]);
#pragma unroll
    for (int j = 0; j < 8; ++j)
      *reinterpret_cast<bf16x8_t*>(&As[r][hf + j * 8]) =
          *reinterpret_cast<bf16x8_t*>(&tmp[j * 8]);
  }
  __syncthreads();
  floatx4 acc[4][4];
#pragma unroll
  for (int i = 0; i < 4; ++i)
#pragma unroll
    for (int j = 0; j < 4; ++j) acc[i][j] = (floatx4){0.f, 0.f, 0.f, 0.f};
  const unsigned short* Ub = Abuf + ((size_t)bl << 21) + c2 * 128;
#pragma unroll
  for (int d0 = 0; d0 < 128; d0 += 32) {
    bf16x8_t af[4], bf[4];
#pragma unroll
    for (int i = 0; i < 4; ++i) {
      const int m = wr * 64 + i * 16 + l15;
      af[i] = *reinterpret_cast<const bf16x8_t*>(&As[m][d0 + quad * 8]);
    }
#pragma unroll
    for (int j = 0; j < 4; ++j) {
      const int n = wc * 64 + j * 16 + l15;
      bf[j] = *reinterpret_cast<const bf16x8_t*>(Ub + ((size_t)n << 14) + d0 + quad * 8);
    }
#pragma unroll
    for (int i = 0; i < 4; ++i)
#pragma unroll
      for (int j = 0; j < 4; ++j)
        acc[i][j] = __builtin_amdgcn_mfma_f32_16x16x32_bf16(af[i], bf[j], acc[i][j], 0, 0, 0);
  }
  const size_t obase = ((size_t)b << 21) + ((size_t)c2 << 14);
#pragma unroll
  for (int i = 0; i < 4; ++i) {
#pragma unroll
    for (int j = 0; j < 4; ++j) {
#pragma unroll
      for (int r = 0; r < 4; ++r) {
        const int h2 = wr * 64 + i * 16 + quad * 4 + r;
        const int w2 = wc * 64 + j * 16 + l15;
        const size_t a = obase + ((size_t)h2 << 7) + w2;
        if (pass == 0)
          out[a] = acc[i][j][r] + lb[h2] + Fi[a] + Fw[a];
        else
          out[a] += acc[i][j][r];
      }
    }
  }
}

extern "C" void kernel_launch(void* const* d_in, const int* in_sizes, int n_in,
                              void* d_out, int out_size, void* d_ws, size_t ws_size,
                              hipStream_t stream) {
  const float* F_i  = (const float*)d_in[0];
  const float* F_w  = (const float*)d_in[1];
  const float* g1   = (const float*)d_in[2];
  const float* g2   = (const float*)d_in[3];
  const float* qw1  = (const float*)d_in[4];
  const float* kw1  = (const float*)d_in[5];
  const float* vw1  = (const float*)d_in[6];
  const float* qw2  = (const float*)d_in[7];
  const float* kw2  = (const float*)d_in[8];
  const float* vw2  = (const float*)d_in[9];
  const float* qb1  = (const float*)d_in[10];
  const float* kb1  = (const float*)d_in[11];
  const float* vb1  = (const float*)d_in[12];
  const float* qb2  = (const float*)d_in[13];
  const float* kb2  = (const float*)d_in[14];
  const float* vb2  = (const float*)d_in[15];
  const float* qdw1 = (const float*)d_in[16];
  const float* kdw1 = (const float*)d_in[17];
  const float* vdw1 = (const float*)d_in[18];
  const float* qdw2 = (const float*)d_in[19];
  const float* kdw2 = (const float*)d_in[20];
  const float* vdw2 = (const float*)d_in[21];
  const float* qdb1 = (const float*)d_in[22];
  const float* kdb1 = (const float*)d_in[23];
  const float* vdb1 = (const float*)d_in[24];
  const float* qdb2 = (const float*)d_in[25];
  const float* kdb2 = (const float*)d_in[26];
  const float* vdb2 = (const float*)d_in[27];
  const float* lw   = (const float*)d_in[28];
  const float* lb   = (const float*)d_in[29];
  float* out = (float*)d_out;

  // ---- workspace (~98 MiB peak) ----
  char* w = (char*)d_ws;
  const size_t NTOT = (size_t)NB * HW;                      // 131072
  float* meanI = (float*)w; w += NTOT * 4;
  float* rstdI = (float*)w; w += NTOT * 4;
  float* meanW = (float*)w; w += NTOT * 4;
  float* rstdW = (float*)w; w += NTOT * 4;
  float* S     = (float*)w; w += (size_t)GB * HW * 4;       // 0.25 MiB
  float* P     = (float*)w; w += (size_t)128 * GB * HW * 4; // 32 MiB
  float* Yq    = (float*)w; w += ((size_t)GB << 21) * 4;    // 32 MiB
  char*  Ykreg = w;         w += ((size_t)GB << 21) * 4;    // 32 MiB (overlaid)
  float* Yk    = (float*)Ykreg;
  unsigned short* Vt   = (unsigned short*)Ykreg;                          // 16 MiB
  unsigned short* Abuf = (unsigned short*)(Ykreg + ((size_t)GB << 21) * 2); // 16 MiB

  dim3 blk(256);
  k_ln_stats<<<dim3(512), blk, 0, stream>>>(F_i, meanI, rstdI);
  k_ln_stats<<<dim3(512), blk, 0, stream>>>(F_w, meanW, rstdW);

  for (int b0 = 0; b0 < NB; b0 += GB) {
    // ---- attention 1: a1 = softmax(Qi^T Kw) ; Aw = a1 @ Vw ; final pass 0 ----
    k_conv1x1_mfma<<<dim3(128, GB), blk, 0, stream>>>(F_i, qw1, qb1, g1, meanI, rstdI, Yq, b0);
    k_conv1x1_mfma<<<dim3(128, GB), blk, 0, stream>>>(F_w, kw2, kb2, g2, meanW, rstdW, Yk, b0);
    k_score_dw<<<dim3(128, GB), blk, 0, stream>>>(Yq, Yk, qdw1, qdb1, kdw2, kdb2, P);
    k_score_reduce<<<dim3(GB * HW / 256), blk, 0, stream>>>(P, S);
    k_softmax<<<dim3(GB * 128), dim3(128), 0, stream>>>(S);
    k_conv1x1_mfma<<<dim3(128, GB), blk, 0, stream>>>(F_w, vw2, vb2, g2, meanW, rstdW, Yq, b0);
    k_dw_t<<<dim3(128, 4, GB), blk, 0, stream>>>(Yq, vdw2, vdb2, Vt);
    k_av_mfma<<<dim3(128, GB), blk, 0, stream>>>(S, Vt, Abuf);
    k_final_mfma<<<dim3(128, GB), blk, 0, stream>>>(Abuf, lw, lb, F_i, F_w, out, 0, b0);

    // ---- attention 2: a2 = softmax(Qw^T Ki) ; Ai = a2 @ Vi ; final pass 1 ----
    k_conv1x1_mfma<<<dim3(128, GB), blk, 0, stream>>>(F_w, qw2, qb2, g2, meanW, rstdW, Yq, b0);
    k_conv1x1_mfma<<<dim3(128, GB), blk, 0, stream>>>(F_i, kw1, kb1, g1, meanI, rstdI, Yk, b0);
    k_score_dw<<<dim3(128, GB), blk, 0, stream>>>(Yq, Yk, qdw2, qdb2, kdw1, kdb1, P);
    k_score_reduce<<<dim3(GB * HW / 256), blk, 0, stream>>>(P, S);
    k_softmax<<<dim3(GB * 128), dim3(128), 0, stream>>>(S);
    k_conv1x1_mfma<<<dim3(128, GB), blk, 0, stream>>>(F_i, vw1, vb1, g1, meanI, rstdI, Yq, b0);
    k_dw_t<<<dim3(128, 4, GB), blk, 0, stream>>>(Yq, vdw1, vdb1, Vt);
    k_av_mfma<<<dim3(128, GB), blk, 0, stream>>>(S, Vt, Abuf);
    k_final_mfma<<<dim3(128, GB), blk, 0, stream>>>(Abuf, lw, lb, F_i, F_w, out, 1, b0);
  }
}

// Round 7
// 838.931 us; speedup vs baseline: 1.7085x; 1.0991x over previous
//
#include <hip/hip_runtime.h>
#include <cstddef>
#include <cstring>

#define HW 16384
#define CC 128
#define NB 8
#define GB 4   // batches per group

typedef short bf16x8_t __attribute__((ext_vector_type(8)));
typedef float floatx4 __attribute__((ext_vector_type(4)));

__device__ inline unsigned short f2bf(float f) {
  unsigned u; __builtin_memcpy(&u, &f, 4);
  u += 0x7fffu + ((u >> 16) & 1u);
  return (unsigned short)(u >> 16);
}
__device__ inline float bf2f(unsigned short s) {
  unsigned u = ((unsigned)s) << 16; float f; __builtin_memcpy(&f, &u, 4);
  return f;
}

// ---------------- LayerNorm stats (mean / rstd per (b,p)), all 8 batches ----
__global__ __launch_bounds__(256) void k_ln_stats(const float* __restrict__ x,
                                                  float* __restrict__ mean,
                                                  float* __restrict__ rstd) {
  int idx = blockIdx.x * 256 + threadIdx.x;   // 0 .. 131071
  int b = idx >> 14;
  int p = idx & (HW - 1);
  const float* xp = x + ((size_t)b << 21) + p;
  float s = 0.f, ss = 0.f;
  for (int c = 0; c < CC; ++c) {
    float v = xp[(size_t)c << 14];
    s += v;
    ss += v * v;
  }
  float m = s * (1.0f / CC);
  float var = ss * (1.0f / CC) - m * m;
  mean[idx] = m;
  rstd[idx] = rsqrtf(var + 1e-5f);
}

// ---------------- split-bf16 MFMA LN+1x1 conv ----------------
// Y[o,p] = sum_c (W[o,c]*g[c]) * (X[c,p]-mu_p)*r_p + bias[o]
// 3 MFMA passes hi*hi + hi*lo + lo*hi  => ~fp32 accuracy (err ~2^-18).
__global__ __launch_bounds__(256) void k_conv1x1_mfma(
    const float* __restrict__ X, const float* __restrict__ W,
    const float* __restrict__ bias, const float* __restrict__ g,
    const float* __restrict__ mean, const float* __restrict__ rstd,
    float* __restrict__ Y, int b0) {
  __shared__ __align__(16) float raw[32][132];   // X chunk [c][p]
  __shared__ __align__(16) short Ah[128][40];    // Wg hi [o][c_local]
  __shared__ __align__(16) short Al[128][40];
  __shared__ __align__(16) short Bh[128][40];    // Xn hi [p][c_local]
  __shared__ __align__(16) short Bl[128][40];
  const int bl = blockIdx.y;
  const int b = b0 + bl;
  const int p0 = blockIdx.x * 128;
  const int t = threadIdx.x;
  const int lane = t & 63, wv = t >> 6;
  const int quad = lane >> 4, l15 = lane & 15;
  const int wr = wv >> 1, wc = wv & 1;

  const int s1c = t >> 3, s1p = (t & 7) * 16;
  const int sao = t >> 1, sas = (t & 1) * 16;
  const int s2p = t & 127, s2o = t >> 7;
  const float mu = mean[b * HW + p0 + s2p];
  const float rs = rstd[b * HW + p0 + s2p];

  const float* Xb = X + ((size_t)b << 21);
  floatx4 acc[4][4];
#pragma unroll
  for (int i = 0; i < 4; ++i)
#pragma unroll
    for (int j = 0; j < 4; ++j) acc[i][j] = (floatx4){0.f, 0.f, 0.f, 0.f};

  for (int k0 = 0; k0 < 128; k0 += 32) {
    {
      const float* xp = Xb + ((size_t)(k0 + s1c) << 14) + p0 + s1p;
#pragma unroll
      for (int u = 0; u < 4; ++u)
        *reinterpret_cast<float4*>(&raw[s1c][s1p + 4 * u]) =
            *reinterpret_cast<const float4*>(xp + 4 * u);
    }
    {
      const float* wp = W + sao * 128 + k0 + sas;
      const float* gp = g + k0 + sas;
      short th[16], tl[16];
#pragma unroll
      for (int j = 0; j < 16; ++j) {
        float v = wp[j] * gp[j];
        unsigned short h = f2bf(v);
        th[j] = (short)h;
        tl[j] = (short)f2bf(v - bf2f(h));
      }
#pragma unroll
      for (int j = 0; j < 2; ++j) {
        *reinterpret_cast<bf16x8_t*>(&Ah[sao][sas + 8 * j]) =
            *reinterpret_cast<bf16x8_t*>(&th[8 * j]);
        *reinterpret_cast<bf16x8_t*>(&Al[sao][sas + 8 * j]) =
            *reinterpret_cast<bf16x8_t*>(&tl[8 * j]);
      }
    }
    __syncthreads();
#pragma unroll
    for (int item = 0; item < 2; ++item) {
      const int oct = s2o + 2 * item;     // 0..3
      short th[8], tl[8];
#pragma unroll
      for (int jj = 0; jj < 8; ++jj) {
        float v = (raw[oct * 8 + jj][s2p] - mu) * rs;
        unsigned short h = f2bf(v);
        th[jj] = (short)h;
        tl[jj] = (short)f2bf(v - bf2f(h));
      }
      *reinterpret_cast<bf16x8_t*>(&Bh[s2p][oct * 8]) =
          *reinterpret_cast<bf16x8_t*>(&th[0]);
      *reinterpret_cast<bf16x8_t*>(&Bl[s2p][oct * 8]) =
          *reinterpret_cast<bf16x8_t*>(&tl[0]);
    }
    __syncthreads();
    bf16x8_t afh[4], afl[4], bfh[4], bfl[4];
#pragma unroll
    for (int i = 0; i < 4; ++i) {
      const int m = wr * 64 + i * 16 + l15;
      afh[i] = *reinterpret_cast<const bf16x8_t*>(&Ah[m][quad * 8]);
      afl[i] = *reinterpret_cast<const bf16x8_t*>(&Al[m][quad * 8]);
    }
#pragma unroll
    for (int j = 0; j < 4; ++j) {
      const int p = wc * 64 + j * 16 + l15;
      bfh[j] = *reinterpret_cast<const bf16x8_t*>(&Bh[p][quad * 8]);
      bfl[j] = *reinterpret_cast<const bf16x8_t*>(&Bl[p][quad * 8]);
    }
#pragma unroll
    for (int i = 0; i < 4; ++i)
#pragma unroll
      for (int j = 0; j < 4; ++j) {
        acc[i][j] = __builtin_amdgcn_mfma_f32_16x16x32_bf16(afh[i], bfh[j], acc[i][j], 0, 0, 0);
        acc[i][j] = __builtin_amdgcn_mfma_f32_16x16x32_bf16(afh[i], bfl[j], acc[i][j], 0, 0, 0);
        acc[i][j] = __builtin_amdgcn_mfma_f32_16x16x32_bf16(afl[i], bfh[j], acc[i][j], 0, 0, 0);
      }
    __syncthreads();
  }
  float* Yb = Y + ((size_t)bl << 21);
#pragma unroll
  for (int i = 0; i < 4; ++i) {
#pragma unroll
    for (int j = 0; j < 4; ++j) {
#pragma unroll
      for (int r = 0; r < 4; ++r) {
        const int o = wr * 64 + i * 16 + quad * 4 + r;
        const int p = p0 + wc * 64 + j * 16 + l15;
        Yb[((size_t)o << 14) + p] = acc[i][j][r] + bias[o];
      }
    }
  }
}

// ---------------- split-bf16 MFMA score GEMM with fused depthwise 3x3 --------
// chunk ch = one channel cc; K-loop 4 x 32 view-rows (h). Output 128x128 (c,d)
// partial into P. 3 MFMA passes per fragment pair => ~fp32 score accuracy.
__global__ __launch_bounds__(256) void k_score_mfma(
    const float* __restrict__ Yq, const float* __restrict__ Yk,
    const float* __restrict__ qdw, const float* __restrict__ qdb,
    const float* __restrict__ kdw, const float* __restrict__ kdb,
    float* __restrict__ P) {
  __shared__ __align__(16) float raw[32][132];   // dw out chunk [h][w]
  __shared__ __align__(16) short Ah[128][40];    // Q side [w][h] hi
  __shared__ __align__(16) short Al[128][40];
  __shared__ __align__(16) short Bh[128][40];    // K side [w][h] hi
  __shared__ __align__(16) short Bl[128][40];
  const int ch = blockIdx.x;
  const int bl = blockIdx.y;
  const int t = threadIdx.x;
  const int lane = t & 63, wv = t >> 6;
  const int quad = lane >> 4, l15 = lane & 15;
  const int wr = wv >> 1, wc = wv & 1;
  const int h_loc = t >> 3;
  const int w0 = (t & 7) * 16;
  const int s2w = t & 127, s2o = t >> 7;
  const int cc = ch;
  const float* Yqb = Yq + ((size_t)bl << 21) + ((size_t)cc << 14);
  const float* Ykb = Yk + ((size_t)bl << 21) + ((size_t)cc << 14);
  const float* qwt = qdw + cc * 9;
  const float* kwt = kdw + cc * 9;
  const float qbv = qdb[cc], kbv = kdb[cc];

  floatx4 acc[4][4];
#pragma unroll
  for (int i = 0; i < 4; ++i)
#pragma unroll
    for (int j = 0; j < 4; ++j) acc[i][j] = (floatx4){0.f, 0.f, 0.f, 0.f};

  for (int k0 = 0; k0 < 128; k0 += 32) {
    const int h = k0 + h_loc;
#pragma unroll
    for (int side = 0; side < 2; ++side) {
      // ---- fused dw 3x3: 16 contiguous w at view-row h ----
      const float* Yc = side ? Ykb : Yqb;
      const float* wt = side ? kwt : qwt;
      const float bias = side ? kbv : qbv;
      float a[16];
#pragma unroll
      for (int j = 0; j < 16; ++j) a[j] = bias;
#pragma unroll
      for (int dy = 0; dy < 3; ++dy) {
        const int hh = h + dy - 1;
        if (hh < 0 || hh > 127) continue;
        const float* rp = Yc + (hh << 7) + w0;
        float4 f0 = *reinterpret_cast<const float4*>(rp);
        float4 f1 = *reinterpret_cast<const float4*>(rp + 4);
        float4 f2 = *reinterpret_cast<const float4*>(rp + 8);
        float4 f3 = *reinterpret_cast<const float4*>(rp + 12);
        float s[18];
        s[1] = f0.x;  s[2] = f0.y;  s[3] = f0.z;  s[4] = f0.w;
        s[5] = f1.x;  s[6] = f1.y;  s[7] = f1.z;  s[8] = f1.w;
        s[9] = f2.x;  s[10] = f2.y; s[11] = f2.z; s[12] = f2.w;
        s[13] = f3.x; s[14] = f3.y; s[15] = f3.z; s[16] = f3.w;
        s[0] = (w0 > 0) ? rp[-1] : 0.f;
        s[17] = (w0 < 112) ? rp[16] : 0.f;
        const float wa = wt[dy * 3 + 0], wb = wt[dy * 3 + 1], wc2 = wt[dy * 3 + 2];
#pragma unroll
        for (int j = 0; j < 16; ++j)
          a[j] = fmaf(s[j], wa, fmaf(s[j + 1], wb, fmaf(s[j + 2], wc2, a[j])));
      }
#pragma unroll
      for (int u = 0; u < 4; ++u)
        *reinterpret_cast<float4*>(&raw[h_loc][w0 + 4 * u]) =
            (float4){a[4 * u], a[4 * u + 1], a[4 * u + 2], a[4 * u + 3]};
      __syncthreads();
      // ---- transpose [h][w] -> [w][h] + hi/lo split ----
      short* dh = side ? &Bh[0][0] : &Ah[0][0];
      short* dl = side ? &Bl[0][0] : &Al[0][0];
#pragma unroll
      for (int item = 0; item < 2; ++item) {
        const int oct = s2o + 2 * item;   // 0..3
        short th[8], tl[8];
#pragma unroll
        for (int jj = 0; jj < 8; ++jj) {
          float v = raw[oct * 8 + jj][s2w];
          unsigned short hb = f2bf(v);
          th[jj] = (short)hb;
          tl[jj] = (short)f2bf(v - bf2f(hb));
        }
        *reinterpret_cast<bf16x8_t*>(&dh[s2w * 40 + oct * 8]) =
            *reinterpret_cast<bf16x8_t*>(&th[0]);
        *reinterpret_cast<bf16x8_t*>(&dl[s2w * 40 + oct * 8]) =
            *reinterpret_cast<bf16x8_t*>(&tl[0]);
      }
      __syncthreads();
    }
    // ---- MFMA, 3 split passes ----
    bf16x8_t afh[4], afl[4], bfh[4], bfl[4];
#pragma unroll
    for (int i = 0; i < 4; ++i) {
      const int m = wr * 64 + i * 16 + l15;
      afh[i] = *reinterpret_cast<const bf16x8_t*>(&Ah[m][quad * 8]);
      afl[i] = *reinterpret_cast<const bf16x8_t*>(&Al[m][quad * 8]);
    }
#pragma unroll
    for (int j = 0; j < 4; ++j) {
      const int n = wc * 64 + j * 16 + l15;
      bfh[j] = *reinterpret_cast<const bf16x8_t*>(&Bh[n][quad * 8]);
      bfl[j] = *reinterpret_cast<const bf16x8_t*>(&Bl[n][quad * 8]);
    }
#pragma unroll
    for (int i = 0; i < 4; ++i)
#pragma unroll
      for (int j = 0; j < 4; ++j) {
        acc[i][j] = __builtin_amdgcn_mfma_f32_16x16x32_bf16(afh[i], bfh[j], acc[i][j], 0, 0, 0);
        acc[i][j] = __builtin_amdgcn_mfma_f32_16x16x32_bf16(afh[i], bfl[j], acc[i][j], 0, 0, 0);
        acc[i][j] = __builtin_amdgcn_mfma_f32_16x16x32_bf16(afl[i], bfh[j], acc[i][j], 0, 0, 0);
      }
  }
  float* Pp = P + ((size_t)(ch * GB + bl) << 14);
#pragma unroll
  for (int i = 0; i < 4; ++i) {
#pragma unroll
    for (int j = 0; j < 4; ++j) {
#pragma unroll
      for (int r = 0; r < 4; ++r) {
        const int c = wr * 64 + i * 16 + quad * 4 + r;
        const int d = wc * 64 + j * 16 + l15;
        Pp[c * 128 + d] = acc[i][j][r];
      }
    }
  }
}

// ---------------- reduce split-K partials -> S (GB batches) ----------------
__global__ __launch_bounds__(256) void k_score_reduce(const float* __restrict__ P,
                                                      float* __restrict__ S) {
  int idx = blockIdx.x * 256 + threadIdx.x;
  int bl = idx >> 14;
  int rem = idx & 16383;
  float s = 0.f;
  for (int c = 0; c < 128; ++c) s += P[((size_t)(c * GB + bl) << 14) + rem];
  S[idx] = s;
}

// ---------------- softmax over rows of 128 ----------------
__global__ __launch_bounds__(128) void k_softmax(float* __restrict__ S) {
  __shared__ float red[128];
  const int row = blockIdx.x;
  const int t = threadIdx.x;
  float v = S[row * 128 + t];
  red[t] = v;
  __syncthreads();
  for (int s = 64; s > 0; s >>= 1) {
    if (t < s) red[t] = fmaxf(red[t], red[t + s]);
    __syncthreads();
  }
  float mx = red[0];
  __syncthreads();
  float e = expf(v - mx);
  red[t] = e;
  __syncthreads();
  for (int s = 64; s > 0; s >>= 1) {
    if (t < s) red[t] += red[t + s];
    __syncthreads();
  }
  S[row * 128 + t] = e / red[0];
}

// ---------------- depthwise 3x3 + transpose: Vt[p][c] bf16 -----------------
__global__ __launch_bounds__(256) void k_dw_t(const float* __restrict__ Y,
                                              const float* __restrict__ Kw,
                                              const float* __restrict__ db,
                                              unsigned short* __restrict__ Vt) {
  __shared__ unsigned short T[128][33];
  const int h = blockIdx.x;
  const int c0 = blockIdx.y * 32;
  const int bl = blockIdx.z;
  const int t = threadIdx.x;
  const int cl = t >> 3;
  const int w0 = (t & 7) * 16;
  const int c = c0 + cl;
  const float* Yc = Y + ((size_t)bl << 21) + ((size_t)c << 14);
  const float* wt = Kw + c * 9;
  float a[16];
#pragma unroll
  for (int j = 0; j < 16; ++j) a[j] = db[c];
#pragma unroll
  for (int dy = 0; dy < 3; ++dy) {
    const int hh = h + dy - 1;
    if (hh < 0 || hh > 127) continue;
    const float* rp = Yc + (hh << 7) + w0;
    float4 f0 = *reinterpret_cast<const float4*>(rp);
    float4 f1 = *reinterpret_cast<const float4*>(rp + 4);
    float4 f2 = *reinterpret_cast<const float4*>(rp + 8);
    float4 f3 = *reinterpret_cast<const float4*>(rp + 12);
    float s[18];
    s[1] = f0.x;  s[2] = f0.y;  s[3] = f0.z;  s[4] = f0.w;
    s[5] = f1.x;  s[6] = f1.y;  s[7] = f1.z;  s[8] = f1.w;
    s[9] = f2.x;  s[10] = f2.y; s[11] = f2.z; s[12] = f2.w;
    s[13] = f3.x; s[14] = f3.y; s[15] = f3.z; s[16] = f3.w;
    s[0] = (w0 > 0) ? rp[-1] : 0.f;
    s[17] = (w0 < 112) ? rp[16] : 0.f;
    const float wa = wt[dy * 3 + 0], wb = wt[dy * 3 + 1], wc2 = wt[dy * 3 + 2];
#pragma unroll
    for (int j = 0; j < 16; ++j)
      a[j] = fmaf(s[j], wa, fmaf(s[j + 1], wb, fmaf(s[j + 2], wc2, a[j])));
  }
#pragma unroll
  for (int j = 0; j < 16; ++j) T[w0 + j][cl] = f2bf(a[j]);
  __syncthreads();
  const int w = t >> 1, half = t & 1;
  unsigned short tmp[16];
#pragma unroll
  for (int j = 0; j < 16; ++j) tmp[j] = T[w][half * 16 + j];
  uint4 v0, v1;
  unsigned* vp0 = reinterpret_cast<unsigned*>(&v0);
  unsigned* vp1 = reinterpret_cast<unsigned*>(&v1);
#pragma unroll
  for (int j = 0; j < 4; ++j) {
    vp0[j] = (unsigned)tmp[2 * j] | ((unsigned)tmp[2 * j + 1] << 16);
    vp1[j] = (unsigned)tmp[8 + 2 * j] | ((unsigned)tmp[8 + 2 * j + 1] << 16);
  }
  unsigned short* dst = Vt + ((size_t)bl << 21) + ((size_t)((h << 7) + w) << 7)
                        + c0 + half * 16;
  *reinterpret_cast<uint4*>(dst) = v0;
  *reinterpret_cast<uint4*>(dst + 8) = v1;
}

// ---------------- MFMA: O[c,p] = sum_d Att[c,d] * V[d,p], Vt layout --------
__global__ __launch_bounds__(256) void k_av_mfma(
    const float* __restrict__ S, const unsigned short* __restrict__ Vt,
    unsigned short* __restrict__ O) {
  __shared__ __align__(16) short As[128][136];
  const int bl = blockIdx.y;
  const int p0 = blockIdx.x * 128;
  const int t = threadIdx.x;
  const int lane = t & 63, wv = t >> 6;
  const int quad = lane >> 4, l15 = lane & 15;
  const int wr = wv >> 1, wc = wv & 1;
  {
    const float* Ab = S + ((size_t)bl << 14);
    const int r = t >> 1, hf = (t & 1) * 64;
    const float* src = Ab + r * 128 + hf;
    short tmp[64];
#pragma unroll
    for (int j = 0; j < 64; ++j) tmp[j] = (short)f2bf(src[j]);
#pragma unroll
    for (int j = 0; j < 8; ++j)
      *reinterpret_cast<bf16x8_t*>(&As[r][hf + j * 8]) =
          *reinterpret_cast<bf16x8_t*>(&tmp[j * 8]);
  }
  __syncthreads();
  floatx4 acc[4][4];
#pragma unroll
  for (int i = 0; i < 4; ++i)
#pragma unroll
    for (int j = 0; j < 4; ++j) acc[i][j] = (floatx4){0.f, 0.f, 0.f, 0.f};
  const unsigned short* Vb = Vt + ((size_t)bl << 21);
#pragma unroll
  for (int d0 = 0; d0 < 128; d0 += 32) {
    bf16x8_t af[4], bf[4];
#pragma unroll
    for (int i = 0; i < 4; ++i) {
      const int m = wr * 64 + i * 16 + l15;
      af[i] = *reinterpret_cast<const bf16x8_t*>(&As[m][d0 + quad * 8]);
    }
#pragma unroll
    for (int j = 0; j < 4; ++j) {
      const int p = p0 + wc * 64 + j * 16 + l15;
      bf[j] = *reinterpret_cast<const bf16x8_t*>(Vb + ((size_t)p << 7) + d0 + quad * 8);
    }
#pragma unroll
    for (int i = 0; i < 4; ++i)
#pragma unroll
      for (int j = 0; j < 4; ++j)
        acc[i][j] = __builtin_amdgcn_mfma_f32_16x16x32_bf16(af[i], bf[j], acc[i][j], 0, 0, 0);
  }
  unsigned short* Ob = O + ((size_t)bl << 21);
#pragma unroll
  for (int i = 0; i < 4; ++i) {
#pragma unroll
    for (int j = 0; j < 4; ++j) {
#pragma unroll
      for (int r = 0; r < 4; ++r) {
        const int c = wr * 64 + i * 16 + quad * 4 + r;
        const int p = p0 + wc * 64 + j * 16 + l15;
        Ob[((size_t)c << 14) + p] = f2bf(acc[i][j][r]);
      }
    }
  }
}

// ---------------- MFMA final: both lw-halves fused, single out write --------
// out[b,c2,h2,w2] = sum_k A1[bl,n=w2,c2*128+k]*lw[h2,k]
//                 + sum_k A2[bl,n=w2,c2*128+k]*lw[h2,128+k] + lb + Fi + Fw
__global__ __launch_bounds__(256) void k_final2_mfma(
    const unsigned short* __restrict__ A1, const unsigned short* __restrict__ A2,
    const float* __restrict__ lw, const float* __restrict__ lb,
    const float* __restrict__ Fi, const float* __restrict__ Fw,
    float* __restrict__ out, int b0) {
  __shared__ __align__(16) short As[128][136];
  const int c2 = blockIdx.x;
  const int bl = blockIdx.y;
  const int b = b0 + bl;
  const int t = threadIdx.x;
  const int lane = t & 63, wv = t >> 6;
  const int quad = lane >> 4, l15 = lane & 15;
  const int wr = wv >> 1, wc = wv & 1;
  floatx4 acc[4][4];
#pragma unroll
  for (int i = 0; i < 4; ++i)
#pragma unroll
    for (int j = 0; j < 4; ++j) acc[i][j] = (floatx4){0.f, 0.f, 0.f, 0.f};
#pragma unroll
  for (int phase = 0; phase < 2; ++phase) {
    {
      const int r = t >> 1, hf = (t & 1) * 64;
      const float* src = lw + r * 256 + phase * 128 + hf;
      short tmp[64];
#pragma unroll
      for (int j = 0; j < 64; ++j) tmp[j] = (short)f2bf(src[j]);
#pragma unroll
      for (int j = 0; j < 8; ++j)
        *reinterpret_cast<bf16x8_t*>(&As[r][hf + j * 8]) =
            *reinterpret_cast<bf16x8_t*>(&tmp[j * 8]);
    }
    __syncthreads();
    const unsigned short* Ub = (phase ? A2 : A1) + ((size_t)bl << 21) + c2 * 128;
#pragma unroll
    for (int d0 = 0; d0 < 128; d0 += 32) {
      bf16x8_t af[4], bf[4];
#pragma unroll
      for (int i = 0; i < 4; ++i) {
        const int m = wr * 64 + i * 16 + l15;
        af[i] = *reinterpret_cast<const bf16x8_t*>(&As[m][d0 + quad * 8]);
      }
#pragma unroll
      for (int j = 0; j < 4; ++j) {
        const int n = wc * 64 + j * 16 + l15;
        bf[j] = *reinterpret_cast<const bf16x8_t*>(Ub + ((size_t)n << 14) + d0 + quad * 8);
      }
#pragma unroll
      for (int i = 0; i < 4; ++i)
#pragma unroll
        for (int j = 0; j < 4; ++j)
          acc[i][j] = __builtin_amdgcn_mfma_f32_16x16x32_bf16(af[i], bf[j], acc[i][j], 0, 0, 0);
    }
    __syncthreads();   // frag reads done before phase-1 restage
  }
  const size_t obase = ((size_t)b << 21) + ((size_t)c2 << 14);
#pragma unroll
  for (int i = 0; i < 4; ++i) {
#pragma unroll
    for (int j = 0; j < 4; ++j) {
#pragma unroll
      for (int r = 0; r < 4; ++r) {
        const int h2 = wr * 64 + i * 16 + quad * 4 + r;
        const int w2 = wc * 64 + j * 16 + l15;
        const size_t a = obase + ((size_t)h2 << 7) + w2;
        out[a] = acc[i][j][r] + lb[h2] + Fi[a] + Fw[a];
      }
    }
  }
}

extern "C" void kernel_launch(void* const* d_in, const int* in_sizes, int n_in,
                              void* d_out, int out_size, void* d_ws, size_t ws_size,
                              hipStream_t stream) {
  const float* F_i  = (const float*)d_in[0];
  const float* F_w  = (const float*)d_in[1];
  const float* g1   = (const float*)d_in[2];
  const float* g2   = (const float*)d_in[3];
  const float* qw1  = (const float*)d_in[4];
  const float* kw1  = (const float*)d_in[5];
  const float* vw1  = (const float*)d_in[6];
  const float* qw2  = (const float*)d_in[7];
  const float* kw2  = (const float*)d_in[8];
  const float* vw2  = (const float*)d_in[9];
  const float* qb1  = (const float*)d_in[10];
  const float* kb1  = (const float*)d_in[11];
  const float* vb1  = (const float*)d_in[12];
  const float* qb2  = (const float*)d_in[13];
  const float* kb2  = (const float*)d_in[14];
  const float* vb2  = (const float*)d_in[15];
  const float* qdw1 = (const float*)d_in[16];
  const float* kdw1 = (const float*)d_in[17];
  const float* vdw1 = (const float*)d_in[18];
  const float* qdw2 = (const float*)d_in[19];
  const float* kdw2 = (const float*)d_in[20];
  const float* vdw2 = (const float*)d_in[21];
  const float* qdb1 = (const float*)d_in[22];
  const float* kdb1 = (const float*)d_in[23];
  const float* vdb1 = (const float*)d_in[24];
  const float* qdb2 = (const float*)d_in[25];
  const float* kdb2 = (const float*)d_in[26];
  const float* vdb2 = (const float*)d_in[27];
  const float* lw   = (const float*)d_in[28];
  const float* lb   = (const float*)d_in[29];
  float* out = (float*)d_out;

  // ---- workspace (~114.25 MiB peak; <=116 MiB proven safe in round 2) ----
  char* w = (char*)d_ws;
  const size_t NTOT = (size_t)NB * HW;                      // 131072
  float* meanI = (float*)w; w += NTOT * 4;
  float* rstdI = (float*)w; w += NTOT * 4;
  float* meanW = (float*)w; w += NTOT * 4;
  float* rstdW = (float*)w; w += NTOT * 4;
  float* S     = (float*)w; w += (size_t)GB * HW * 4;       // 0.25 MiB
  float* P     = (float*)w; w += (size_t)128 * GB * HW * 4; // 32 MiB
  float* Yq    = (float*)w; w += ((size_t)GB << 21) * 4;    // 32 MiB
  char*  Ykreg = w;         w += ((size_t)GB << 21) * 4;    // 32 MiB (overlaid)
  float* Yk    = (float*)Ykreg;
  unsigned short* Vt = (unsigned short*)Ykreg;                            // 16 MiB
  unsigned short* A2 = (unsigned short*)(Ykreg + ((size_t)GB << 21) * 2); // 16 MiB
  unsigned short* A1 = (unsigned short*)w; w += ((size_t)GB << 21) * 2;   // 16 MiB

  dim3 blk(256);
  k_ln_stats<<<dim3(512), blk, 0, stream>>>(F_i, meanI, rstdI);
  k_ln_stats<<<dim3(512), blk, 0, stream>>>(F_w, meanW, rstdW);

  for (int b0 = 0; b0 < NB; b0 += GB) {
    // ---- attention 1: a1 = softmax(Qi^T Kw) ; Aw = a1 @ Vw -> A1 ----
    k_conv1x1_mfma<<<dim3(128, GB), blk, 0, stream>>>(F_i, qw1, qb1, g1, meanI, rstdI, Yq, b0);
    k_conv1x1_mfma<<<dim3(128, GB), blk, 0, stream>>>(F_w, kw2, kb2, g2, meanW, rstdW, Yk, b0);
    k_score_mfma<<<dim3(128, GB), blk, 0, stream>>>(Yq, Yk, qdw1, qdb1, kdw2, kdb2, P);
    k_score_reduce<<<dim3(GB * HW / 256), blk, 0, stream>>>(P, S);
    k_softmax<<<dim3(GB * 128), dim3(128), 0, stream>>>(S);
    k_conv1x1_mfma<<<dim3(128, GB), blk, 0, stream>>>(F_w, vw2, vb2, g2, meanW, rstdW, Yq, b0);
    k_dw_t<<<dim3(128, 4, GB), blk, 0, stream>>>(Yq, vdw2, vdb2, Vt);
    k_av_mfma<<<dim3(128, GB), blk, 0, stream>>>(S, Vt, A1);

    // ---- attention 2: a2 = softmax(Qw^T Ki) ; Ai = a2 @ Vi -> A2 ----
    k_conv1x1_mfma<<<dim3(128, GB), blk, 0, stream>>>(F_w, qw2, qb2, g2, meanW, rstdW, Yq, b0);
    k_conv1x1_mfma<<<dim3(128, GB), blk, 0, stream>>>(F_i, kw1, kb1, g1, meanI, rstdI, Yk, b0);
    k_score_mfma<<<dim3(128, GB), blk, 0, stream>>>(Yq, Yk, qdw2, qdb2, kdw1, kdb1, P);
    k_score_reduce<<<dim3(GB * HW / 256), blk, 0, stream>>>(P, S);
    k_softmax<<<dim3(GB * 128), dim3(128), 0, stream>>>(S);
    k_conv1x1_mfma<<<dim3(128, GB), blk, 0, stream>>>(F_i, vw1, vb1, g1, meanI, rstdI, Yq, b0);
    k_dw_t<<<dim3(128, 4, GB), blk, 0, stream>>>(Yq, vdw1, vdb1, Vt);
    k_av_mfma<<<dim3(128, GB), blk, 0, stream>>>(S, Vt, A2);

    // ---- fused final linear + residual (single out write) ----
    k_final2_mfma<<<dim3(128, GB), blk, 0, stream>>>(A1, A2, lw, lb, F_i, F_w, out, b0);
  }
}